// Round 1
// baseline (525.247 us; speedup 1.0000x reference)
//
#include <hip/hip_runtime.h>

#define N_NODES 10000
#define N_EDGES 320000
#define NG      2
#define BATCH   4
#define F0      64
#define F1      128
#define F2      128
// B*F0 = 256 floats per node (layer-1 working vectors), B*F1 = 512

// ---------------------------------------------------------------- CSR build
__global__ void hist_kernel(const int* __restrict__ ei, int* __restrict__ cnt) {
    int j = blockIdx.x * 256 + threadIdx.x;
    if (j >= NG * N_EDGES) return;
    int e = j / N_EDGES, t = j - e * N_EDGES;
    int r = ei[e * 2 * N_EDGES + t];
    atomicAdd(&cnt[e * N_NODES + r], 1);
}

__global__ void prefix_kernel(const int* __restrict__ cnt, int* __restrict__ row_start) {
    // one block per GSO, 256 threads, chunked Hillis-Steele scan
    __shared__ int buf[256];
    __shared__ int carry;
    int e = blockIdx.x;
    int t = threadIdx.x;
    if (t == 0) carry = 0;
    __syncthreads();
    for (int base = 0; base < N_NODES; base += 256) {
        int i = base + t;
        int v = (i < N_NODES) ? cnt[e * N_NODES + i] : 0;
        buf[t] = v;
        __syncthreads();
        for (int off = 1; off < 256; off <<= 1) {
            int x = (t >= off) ? buf[t - off] : 0;
            __syncthreads();
            buf[t] += x;
            __syncthreads();
        }
        int incl = buf[t];
        int excl = incl - v;
        if (i < N_NODES) row_start[e * (N_NODES + 1) + i] = carry + excl;
        __syncthreads();
        if (t == 255) carry += incl;
        __syncthreads();
    }
    if (t == 0) row_start[e * (N_NODES + 1) + N_NODES] = carry;
}

__global__ void scatter_kernel(const int* __restrict__ ei, const float* __restrict__ ev,
                               const int* __restrict__ row_start, int* __restrict__ cursor,
                               int* __restrict__ ccol, float* __restrict__ cval) {
    int j = blockIdx.x * 256 + threadIdx.x;
    if (j >= NG * N_EDGES) return;
    int e = j / N_EDGES, t = j - e * N_EDGES;
    int r = ei[e * 2 * N_EDGES + t];
    int c = ei[e * 2 * N_EDGES + N_EDGES + t];
    float v = ev[e * N_EDGES + t];
    int pos = row_start[e * (N_NODES + 1) + r] + atomicAdd(&cursor[e * N_NODES + r], 1);
    ccol[e * N_EDGES + pos] = c;
    cval[e * N_EDGES + pos] = v;
}

// ---------------------------------------------------------------- layout: x[B,N,F0] -> z0[N,B,F0]
__global__ void transpose_kernel(const float* __restrict__ x, float* __restrict__ z0) {
    int idx = blockIdx.x * 256 + threadIdx.x;   // grid covers N*B*F0 exactly
    int n = idx >> 8, rem = idx & 255, b = rem >> 6, f = rem & 63;
    z0[idx] = x[b * (N_NODES * F0) + n * F0 + f];
}

// ---------------------------------------------------------------- SpMM (CSR, no atomics)
// block = node (2N blocks: first N -> gso0, rest gso1); thread = (b,f) of 256
__global__ void spmm_kernel(const int* __restrict__ ccol, const float* __restrict__ cval,
                            const int* __restrict__ row_start,
                            const float* __restrict__ zin0, const float* __restrict__ zin1,
                            float* __restrict__ zout0, float* __restrict__ zout1) {
    int blk = blockIdx.x;
    int e = (blk >= N_NODES) ? 1 : 0;
    int i = blk - e * N_NODES;
    const float* zin = e ? zin1 : zin0;
    float* zout = e ? zout1 : zout0;
    int s = row_start[e * (N_NODES + 1) + i];
    int send = row_start[e * (N_NODES + 1) + i + 1];
    int t = threadIdx.x;
    float acc = 0.f;
    for (int p = s; p < send; ++p) {
        int c = ccol[e * N_EDGES + p];
        float v = cval[e * N_EDGES + p];
        acc += v * zin[c * 256 + t];
    }
    zout[i * 256 + t] = acc;
}

// ---------------------------------------------------------------- weight prep: Wc[5][64][128]
// s=0: W1[0,0]+W1[1,0]; s=1: W1[0,1]; s=2: W1[0,2]; s=3: W1[1,1]; s=4: W1[1,2]
__global__ void prep_w_kernel(const float* __restrict__ W1, float* __restrict__ Wc) {
    int idx = blockIdx.x * 256 + threadIdx.x;   // grid covers 5*8192 exactly
    int s = idx / 8192, rem = idx - s * 8192;
    float v;
    if (s == 0)      v = W1[0 * 8192 + rem] + W1[3 * 8192 + rem];
    else if (s == 1) v = W1[1 * 8192 + rem];
    else if (s == 2) v = W1[2 * 8192 + rem];
    else if (s == 3) v = W1[4 * 8192 + rem];
    else             v = W1[5 * 8192 + rem];
    Wc[idx] = v;
}

// ---------------------------------------------------------------- fused layer-1 GEMM
// h[m,0:128] = b1 + sum_s z_s[m,0:64] @ Wc[s]   (m = n*4+b, M = 40000)
__global__ __launch_bounds__(256) void gemm_kernel(
        const float* __restrict__ z0,  const float* __restrict__ z11,
        const float* __restrict__ z12, const float* __restrict__ z21,
        const float* __restrict__ z22, const float* __restrict__ Wc,
        const float* __restrict__ b1,  float* __restrict__ h) {
    __shared__ float Ws[64 * 128];    // 32 KB
    __shared__ float Zs[32 * 65];     // padded: bank = (row + k) % 32
    int t  = threadIdx.x;
    int tx = t & 31;        // col group: cols tx*4 .. tx*4+3
    int ty = t >> 5;        // row group: rows ty*4 .. ty*4+3
    int row0 = blockIdx.x * 32;
    float acc[4][4];
    #pragma unroll
    for (int r = 0; r < 4; ++r)
        #pragma unroll
        for (int c = 0; c < 4; ++c) acc[r][c] = 0.f;

    #pragma unroll
    for (int s = 0; s < 5; ++s) {
        const float* zsrc = (s == 0) ? z0 : (s == 1) ? z11 : (s == 2) ? z12
                          : (s == 3) ? z21 : z22;
        const float4* wsrc = (const float4*)(Wc + s * 8192);
        float4* wdst = (float4*)Ws;
        #pragma unroll
        for (int i = 0; i < 8; ++i) wdst[i * 256 + t] = wsrc[i * 256 + t];
        const float* zbase = zsrc + row0 * 64;
        #pragma unroll
        for (int i = 0; i < 8; ++i) {
            int e = i * 256 + t;
            Zs[(e >> 6) * 65 + (e & 63)] = zbase[e];
        }
        __syncthreads();
        #pragma unroll 4
        for (int k = 0; k < 64; ++k) {
            float4 wv = *(const float4*)&Ws[k * 128 + tx * 4];
            #pragma unroll
            for (int r = 0; r < 4; ++r) {
                float zr = Zs[(ty * 4 + r) * 65 + k];
                acc[r][0] += zr * wv.x;
                acc[r][1] += zr * wv.y;
                acc[r][2] += zr * wv.z;
                acc[r][3] += zr * wv.w;
            }
        }
        __syncthreads();
    }
    float4 bv = *(const float4*)&b1[tx * 4];
    #pragma unroll
    for (int r = 0; r < 4; ++r) {
        int row = row0 + ty * 4 + r;
        float4 o;
        o.x = acc[r][0] + bv.x;
        o.y = acc[r][1] + bv.y;
        o.z = acc[r][2] + bv.z;
        o.w = acc[r][3] + bv.w;
        *(float4*)&h[row * 128 + tx * 4] = o;
    }
}

// ---------------------------------------------------------------- layer-2 row-0 propagation vectors
__global__ void r1_kernel(const int* __restrict__ ei, const float* __restrict__ ev,
                          float* __restrict__ r1) {
    int j = blockIdx.x * 256 + threadIdx.x;
    if (j >= NG * N_EDGES) return;
    int e = j / N_EDGES, t = j - e * N_EDGES;
    if (ei[e * 2 * N_EDGES + t] == 0) {
        int c = ei[e * 2 * N_EDGES + N_EDGES + t];
        atomicAdd(&r1[e * N_NODES + c], ev[e * N_EDGES + t]);
    }
}

__global__ void r2_kernel(const int* __restrict__ ei, const float* __restrict__ ev,
                          const float* __restrict__ r1, float* __restrict__ r2) {
    int j = blockIdx.x * 256 + threadIdx.x;
    if (j >= NG * N_EDGES) return;
    int e = j / N_EDGES, t = j - e * N_EDGES;
    float w = r1[e * N_NODES + ei[e * 2 * N_EDGES + t]];
    if (w != 0.f) {
        int c = ei[e * 2 * N_EDGES + N_EDGES + t];
        atomicAdd(&r2[e * N_NODES + c], w * ev[e * N_EDGES + t]);
    }
}

// q[ek][b*128+f1] = sum_n r_ek[n] * h[n,b,f1];  ek: 0=(e0,k1) 1=(e0,k2) 2=(e1,k1) 3=(e1,k2)
__global__ void q_kernel(const float* __restrict__ h, const float* __restrict__ r1,
                         const float* __restrict__ r2, float* __restrict__ q) {
    int t = threadIdx.x;                 // 512 threads = (b,f1)
    int n0 = blockIdx.x * 64;
    int n1 = n0 + 64; if (n1 > N_NODES) n1 = N_NODES;
    float a0 = 0.f, a1 = 0.f, a2 = 0.f, a3 = 0.f;
    for (int n = n0; n < n1; ++n) {
        float w0 = r1[n];
        float w1 = r2[n];
        float w2 = r1[N_NODES + n];
        float w3 = r2[N_NODES + n];
        if (w0 == 0.f && w1 == 0.f && w2 == 0.f && w3 == 0.f) continue;
        float hv = h[n * 512 + t];
        a0 += w0 * hv; a1 += w1 * hv; a2 += w2 * hv; a3 += w3 * hv;
    }
    if (a0 != 0.f) atomicAdd(&q[0 * 512 + t], a0);
    if (a1 != 0.f) atomicAdd(&q[1 * 512 + t], a1);
    if (a2 != 0.f) atomicAdd(&q[2 * 512 + t], a2);
    if (a3 != 0.f) atomicAdd(&q[3 * 512 + t], a3);
}

// out[b,f2] = b2[f2] + h[0,b,:]·(W2[0,0]+W2[1,0]) + q0·W2[0,1] + q1·W2[0,2] + q2·W2[1,1] + q3·W2[1,2]
__global__ void final_kernel(const float* __restrict__ h, const float* __restrict__ q,
                             const float* __restrict__ W2, const float* __restrict__ b2,
                             float* __restrict__ out) {
    int t = threadIdx.x;               // 512
    int b = t >> 7, f2 = t & 127;
    int f1_0 = blockIdx.x * 16;        // 8 blocks x 16 f1 each
    float acc = (blockIdx.x == 0) ? b2[f2] : 0.f;
    for (int f1 = f1_0; f1 < f1_0 + 16; ++f1) {
        int wi = f1 * 128 + f2;
        float w00 = W2[0 * 16384 + wi] + W2[3 * 16384 + wi];
        acc += h[b * 128 + f1] * w00;
        acc += q[0 * 512 + b * 128 + f1] * W2[1 * 16384 + wi];
        acc += q[1 * 512 + b * 128 + f1] * W2[2 * 16384 + wi];
        acc += q[2 * 512 + b * 128 + f1] * W2[4 * 16384 + wi];
        acc += q[3 * 512 + b * 128 + f1] * W2[5 * 16384 + wi];
    }
    atomicAdd(&out[b * 128 + f2], acc);
}

// ----------------------------------------------------------------
extern "C" void kernel_launch(void* const* d_in, const int* in_sizes, int n_in,
                              void* d_out, int out_size, void* d_ws, size_t ws_size,
                              hipStream_t stream) {
    const float* x  = (const float*)d_in[0];
    const int*   ei = (const int*)d_in[1];
    const float* ev = (const float*)d_in[2];
    const float* W1 = (const float*)d_in[3];
    const float* b1 = (const float*)d_in[4];
    const float* W2 = (const float*)d_in[5];
    const float* b2 = (const float*)d_in[6];
    float* out = (float*)d_out;

    char* ws = (char*)d_ws;
    size_t off = 0;
    auto alloc = [&](size_t bytes) { size_t o = off; off += (bytes + 255) & ~(size_t)255; return o; };
    const size_t ZB  = (size_t)N_NODES * BATCH * F0 * 4;      // 10.24 MB per z buffer
    size_t o_z0  = alloc(ZB);
    size_t o_z11 = alloc(ZB);
    size_t o_z12 = alloc(ZB);
    size_t o_z21 = alloc(ZB);
    size_t o_z22 = alloc(ZB);
    size_t o_h   = alloc((size_t)N_NODES * BATCH * F1 * 4);   // 20.48 MB
    size_t o_ccol = alloc((size_t)NG * N_EDGES * 4);
    size_t o_cval = alloc((size_t)NG * N_EDGES * 4);
    size_t o_rs   = alloc((size_t)NG * (N_NODES + 1) * 4);
    size_t o_wc   = alloc((size_t)5 * 64 * 128 * 4);
    size_t o_zero = off;                                      // zeroed region starts here
    size_t o_cnt    = alloc((size_t)NG * N_NODES * 4);
    size_t o_cursor = alloc((size_t)NG * N_NODES * 4);
    size_t o_r      = alloc((size_t)2 * NG * N_NODES * 4);    // r1[2][N] then r2[2][N]
    size_t o_q      = alloc((size_t)4 * 512 * 4);
    size_t zero_bytes = off - o_zero;

    float* z0  = (float*)(ws + o_z0);
    float* z11 = (float*)(ws + o_z11);
    float* z12 = (float*)(ws + o_z12);
    float* z21 = (float*)(ws + o_z21);
    float* z22 = (float*)(ws + o_z22);
    float* h   = (float*)(ws + o_h);
    int*   ccol = (int*)(ws + o_ccol);
    float* cval = (float*)(ws + o_cval);
    int*   rs   = (int*)(ws + o_rs);
    float* Wc   = (float*)(ws + o_wc);
    int*   cnt    = (int*)(ws + o_cnt);
    int*   cursor = (int*)(ws + o_cursor);
    float* r1   = (float*)(ws + o_r);
    float* r2   = r1 + 2 * N_NODES;
    float* q    = (float*)(ws + o_q);

    hipMemsetAsync(ws + o_zero, 0, zero_bytes, stream);
    hipMemsetAsync(out, 0, 512 * sizeof(float), stream);

    hist_kernel   <<<2500, 256, 0, stream>>>(ei, cnt);
    prefix_kernel <<<2,    256, 0, stream>>>(cnt, rs);
    scatter_kernel<<<2500, 256, 0, stream>>>(ei, ev, rs, cursor, ccol, cval);
    transpose_kernel<<<10000, 256, 0, stream>>>(x, z0);
    prep_w_kernel <<<160,  256, 0, stream>>>(W1, Wc);
    spmm_kernel   <<<2 * N_NODES, 256, 0, stream>>>(ccol, cval, rs, z0,  z0,  z11, z21);
    spmm_kernel   <<<2 * N_NODES, 256, 0, stream>>>(ccol, cval, rs, z11, z21, z12, z22);
    gemm_kernel   <<<1250, 256, 0, stream>>>(z0, z11, z12, z21, z22, Wc, b1, h);
    r1_kernel     <<<2500, 256, 0, stream>>>(ei, ev, r1);
    r2_kernel     <<<2500, 256, 0, stream>>>(ei, ev, r1, r2);
    q_kernel      <<<157,  512, 0, stream>>>(h, r1, r2, q);
    final_kernel  <<<8,    512, 0, stream>>>(h, q, W2, b2, out);
}

// Round 2
// 402.592 us; speedup vs baseline: 1.3047x; 1.3047x over previous
//
#include <hip/hip_runtime.h>

#define N_NODES 10000
#define N_EDGES 320000
#define NG      2
#define BATCH   4
#define F0      64
#define F1      128
#define F2      128
// B*F0 = 256 floats per node (layer-1 working vectors), B*F1 = 512

// ---------------------------------------------------------------- CSR build
__global__ void hist_kernel(const int* __restrict__ ei, int* __restrict__ cnt) {
    int j = blockIdx.x * 256 + threadIdx.x;
    if (j >= NG * N_EDGES) return;
    int e = j / N_EDGES, t = j - e * N_EDGES;
    int r = ei[e * 2 * N_EDGES + t];
    atomicAdd(&cnt[e * N_NODES + r], 1);
}

__global__ void prefix_kernel(const int* __restrict__ cnt, int* __restrict__ row_start) {
    // one block per GSO, 256 threads, chunked Hillis-Steele scan
    __shared__ int buf[256];
    __shared__ int carry;
    int e = blockIdx.x;
    int t = threadIdx.x;
    if (t == 0) carry = 0;
    __syncthreads();
    for (int base = 0; base < N_NODES; base += 256) {
        int i = base + t;
        int v = (i < N_NODES) ? cnt[e * N_NODES + i] : 0;
        buf[t] = v;
        __syncthreads();
        for (int off = 1; off < 256; off <<= 1) {
            int x = (t >= off) ? buf[t - off] : 0;
            __syncthreads();
            buf[t] += x;
            __syncthreads();
        }
        int incl = buf[t];
        int excl = incl - v;
        if (i < N_NODES) row_start[e * (N_NODES + 1) + i] = carry + excl;
        __syncthreads();
        if (t == 255) carry += incl;
        __syncthreads();
    }
    if (t == 0) row_start[e * (N_NODES + 1) + N_NODES] = carry;
}

__global__ void scatter_kernel(const int* __restrict__ ei, const float* __restrict__ ev,
                               const int* __restrict__ row_start, int* __restrict__ cursor,
                               int* __restrict__ ccol, float* __restrict__ cval) {
    int j = blockIdx.x * 256 + threadIdx.x;
    if (j >= NG * N_EDGES) return;
    int e = j / N_EDGES, t = j - e * N_EDGES;
    int r = ei[e * 2 * N_EDGES + t];
    int c = ei[e * 2 * N_EDGES + N_EDGES + t];
    float v = ev[e * N_EDGES + t];
    int pos = row_start[e * (N_NODES + 1) + r] + atomicAdd(&cursor[e * N_NODES + r], 1);
    ccol[e * N_EDGES + pos] = c;
    cval[e * N_EDGES + pos] = v;
}

// ---------------------------------------------------------------- layout: x[B,N,F0] -> z0[N,B,F0]
__global__ void transpose_kernel(const float* __restrict__ x, float* __restrict__ z0) {
    int idx = blockIdx.x * 256 + threadIdx.x;   // grid covers N*B*F0 exactly
    int n = idx >> 8, rem = idx & 255, b = rem >> 6, f = rem & 63;
    z0[idx] = x[b * (N_NODES * F0) + n * F0 + f];
}

// ---------------------------------------------------------------- SpMM (CSR, no atomics)
// block = row (node, gso). 4 waves; wave w handles edges p = s+w, s+w+4, ...
// Each lane gathers float4 (16 B) -> one wave moves the full 1 KB node vector
// per instruction. Unroll x2 so each wave keeps 2 gathers + 2 (c,v) loads in
// flight; 4 waves/block => 8 edges in flight per block (was 1 serial).
__global__ __launch_bounds__(256) void spmm_kernel(
        const int* __restrict__ ccol, const float* __restrict__ cval,
        const int* __restrict__ row_start,
        const float* __restrict__ zin0, const float* __restrict__ zin1,
        float* __restrict__ zout0, float* __restrict__ zout1) {
    __shared__ float4 red[3][64];
    int blk = blockIdx.x;
    int e = (blk >= N_NODES) ? 1 : 0;
    int i = blk - e * N_NODES;
    const float4* zin = (const float4*)(e ? zin1 : zin0);
    float4* zout = (float4*)(e ? zout1 : zout0);
    const int*   cc = ccol + e * N_EDGES;
    const float* cv = cval + e * N_EDGES;
    int s    = row_start[e * (N_NODES + 1) + i];
    int send = row_start[e * (N_NODES + 1) + i + 1];
    int t = threadIdx.x;
    int w = t >> 6, l = t & 63;
    float4 acc = make_float4(0.f, 0.f, 0.f, 0.f);
    int p = s + w;
    for (; p + 4 < send; p += 8) {
        int   c0 = cc[p];     float v0 = cv[p];
        int   c1 = cc[p + 4]; float v1 = cv[p + 4];
        float4 za = zin[c0 * 64 + l];
        float4 zb = zin[c1 * 64 + l];
        acc.x += v0 * za.x + v1 * zb.x;
        acc.y += v0 * za.y + v1 * zb.y;
        acc.z += v0 * za.z + v1 * zb.z;
        acc.w += v0 * za.w + v1 * zb.w;
    }
    if (p < send) {
        int c0 = cc[p]; float v0 = cv[p];
        float4 za = zin[c0 * 64 + l];
        acc.x += v0 * za.x; acc.y += v0 * za.y;
        acc.z += v0 * za.z; acc.w += v0 * za.w;
    }
    if (w) red[w - 1][l] = acc;
    __syncthreads();
    if (w == 0) {
        float4 r0 = red[0][l], r1 = red[1][l], r2 = red[2][l];
        acc.x += r0.x + r1.x + r2.x;
        acc.y += r0.y + r1.y + r2.y;
        acc.z += r0.z + r1.z + r2.z;
        acc.w += r0.w + r1.w + r2.w;
        zout[i * 64 + l] = acc;
    }
}

// ---------------------------------------------------------------- weight prep: Wc[5][64][128]
// s=0: W1[0,0]+W1[1,0]; s=1: W1[0,1]; s=2: W1[0,2]; s=3: W1[1,1]; s=4: W1[1,2]
__global__ void prep_w_kernel(const float* __restrict__ W1, float* __restrict__ Wc) {
    int idx = blockIdx.x * 256 + threadIdx.x;   // grid covers 5*8192 exactly
    int s = idx / 8192, rem = idx - s * 8192;
    float v;
    if (s == 0)      v = W1[0 * 8192 + rem] + W1[3 * 8192 + rem];
    else if (s == 1) v = W1[1 * 8192 + rem];
    else if (s == 2) v = W1[2 * 8192 + rem];
    else if (s == 3) v = W1[4 * 8192 + rem];
    else             v = W1[5 * 8192 + rem];
    Wc[idx] = v;
}

// ---------------------------------------------------------------- fused layer-1 GEMM
// h[m,0:128] = b1 + sum_s z_s[m,0:64] @ Wc[s]   (m = n*4+b, M = 40000)
// Inner loop: k-blocked x4; all LDS reads are b128 (8 per 64 FMAs).
__global__ __launch_bounds__(256) void gemm_kernel(
        const float* __restrict__ z0,  const float* __restrict__ z11,
        const float* __restrict__ z12, const float* __restrict__ z21,
        const float* __restrict__ z22, const float* __restrict__ Wc,
        const float* __restrict__ b1,  float* __restrict__ h) {
    __shared__ float Ws[64 * 128];    // 32 KB
    __shared__ float Zs[32 * 68];     // pad 68: float4-aligned, 4-bank row shift
    int t  = threadIdx.x;
    int tx = t & 31;        // col group: cols tx*4 .. tx*4+3
    int ty = t >> 5;        // row group: rows ty*4 .. ty*4+3
    int row0 = blockIdx.x * 32;
    float acc[4][4];
    #pragma unroll
    for (int r = 0; r < 4; ++r)
        #pragma unroll
        for (int c = 0; c < 4; ++c) acc[r][c] = 0.f;

    #pragma unroll
    for (int s = 0; s < 5; ++s) {
        const float* zsrc = (s == 0) ? z0 : (s == 1) ? z11 : (s == 2) ? z12
                          : (s == 3) ? z21 : z22;
        const float4* wsrc = (const float4*)(Wc + s * 8192);
        float4* wdst = (float4*)Ws;
        #pragma unroll
        for (int i = 0; i < 8; ++i) wdst[i * 256 + t] = wsrc[i * 256 + t];
        const float* zbase = zsrc + row0 * 64;
        #pragma unroll
        for (int i = 0; i < 2; ++i) {
            int eidx = i * 1024 + t * 4;
            int zrow = eidx >> 6, zcol = eidx & 63;
            *(float4*)&Zs[zrow * 68 + zcol] = *(const float4*)&zbase[eidx];
        }
        __syncthreads();
        for (int k0 = 0; k0 < 64; k0 += 4) {
            float za[4][4];
            #pragma unroll
            for (int r = 0; r < 4; ++r) {
                float4 zv = *(const float4*)&Zs[(ty * 4 + r) * 68 + k0];
                za[r][0] = zv.x; za[r][1] = zv.y; za[r][2] = zv.z; za[r][3] = zv.w;
            }
            #pragma unroll
            for (int kk = 0; kk < 4; ++kk) {
                float4 wv = *(const float4*)&Ws[(k0 + kk) * 128 + tx * 4];
                #pragma unroll
                for (int r = 0; r < 4; ++r) {
                    acc[r][0] += za[r][kk] * wv.x;
                    acc[r][1] += za[r][kk] * wv.y;
                    acc[r][2] += za[r][kk] * wv.z;
                    acc[r][3] += za[r][kk] * wv.w;
                }
            }
        }
        __syncthreads();
    }
    float4 bv = *(const float4*)&b1[tx * 4];
    #pragma unroll
    for (int r = 0; r < 4; ++r) {
        int row = row0 + ty * 4 + r;
        float4 o;
        o.x = acc[r][0] + bv.x;
        o.y = acc[r][1] + bv.y;
        o.z = acc[r][2] + bv.z;
        o.w = acc[r][3] + bv.w;
        *(float4*)&h[row * 128 + tx * 4] = o;
    }
}

// ---------------------------------------------------------------- layer-2 row-0 propagation vectors
__global__ void r1_kernel(const int* __restrict__ ei, const float* __restrict__ ev,
                          float* __restrict__ r1) {
    int j = blockIdx.x * 256 + threadIdx.x;
    if (j >= NG * N_EDGES) return;
    int e = j / N_EDGES, t = j - e * N_EDGES;
    if (ei[e * 2 * N_EDGES + t] == 0) {
        int c = ei[e * 2 * N_EDGES + N_EDGES + t];
        atomicAdd(&r1[e * N_NODES + c], ev[e * N_EDGES + t]);
    }
}

__global__ void r2_kernel(const int* __restrict__ ei, const float* __restrict__ ev,
                          const float* __restrict__ r1, float* __restrict__ r2) {
    int j = blockIdx.x * 256 + threadIdx.x;
    if (j >= NG * N_EDGES) return;
    int e = j / N_EDGES, t = j - e * N_EDGES;
    float w = r1[e * N_NODES + ei[e * 2 * N_EDGES + t]];
    if (w != 0.f) {
        int c = ei[e * 2 * N_EDGES + N_EDGES + t];
        atomicAdd(&r2[e * N_NODES + c], w * ev[e * N_EDGES + t]);
    }
}

// q[ek][b*128+f1] = sum_n r_ek[n] * h[n,b,f1];  ek: 0=(e0,k1) 1=(e0,k2) 2=(e1,k1) 3=(e1,k2)
__global__ void q_kernel(const float* __restrict__ h, const float* __restrict__ r1,
                         const float* __restrict__ r2, float* __restrict__ q) {
    int t = threadIdx.x;                 // 512 threads = (b,f1)
    int n0 = blockIdx.x * 64;
    int n1 = n0 + 64; if (n1 > N_NODES) n1 = N_NODES;
    float a0 = 0.f, a1 = 0.f, a2 = 0.f, a3 = 0.f;
    for (int n = n0; n < n1; ++n) {
        float w0 = r1[n];
        float w1 = r2[n];
        float w2 = r1[N_NODES + n];
        float w3 = r2[N_NODES + n];
        if (w0 == 0.f && w1 == 0.f && w2 == 0.f && w3 == 0.f) continue;
        float hv = h[n * 512 + t];
        a0 += w0 * hv; a1 += w1 * hv; a2 += w2 * hv; a3 += w3 * hv;
    }
    if (a0 != 0.f) atomicAdd(&q[0 * 512 + t], a0);
    if (a1 != 0.f) atomicAdd(&q[1 * 512 + t], a1);
    if (a2 != 0.f) atomicAdd(&q[2 * 512 + t], a2);
    if (a3 != 0.f) atomicAdd(&q[3 * 512 + t], a3);
}

// out[b,f2] = b2[f2] + h[0,b,:]·(W2[0,0]+W2[1,0]) + q0·W2[0,1] + q1·W2[0,2] + q2·W2[1,1] + q3·W2[1,2]
__global__ void final_kernel(const float* __restrict__ h, const float* __restrict__ q,
                             const float* __restrict__ W2, const float* __restrict__ b2,
                             float* __restrict__ out) {
    int t = threadIdx.x;               // 512
    int b = t >> 7, f2 = t & 127;
    int f1_0 = blockIdx.x * 16;        // 8 blocks x 16 f1 each
    float acc = (blockIdx.x == 0) ? b2[f2] : 0.f;
    for (int f1 = f1_0; f1 < f1_0 + 16; ++f1) {
        int wi = f1 * 128 + f2;
        float w00 = W2[0 * 16384 + wi] + W2[3 * 16384 + wi];
        acc += h[b * 128 + f1] * w00;
        acc += q[0 * 512 + b * 128 + f1] * W2[1 * 16384 + wi];
        acc += q[1 * 512 + b * 128 + f1] * W2[2 * 16384 + wi];
        acc += q[2 * 512 + b * 128 + f1] * W2[4 * 16384 + wi];
        acc += q[3 * 512 + b * 128 + f1] * W2[5 * 16384 + wi];
    }
    atomicAdd(&out[b * 128 + f2], acc);
}

// ----------------------------------------------------------------
extern "C" void kernel_launch(void* const* d_in, const int* in_sizes, int n_in,
                              void* d_out, int out_size, void* d_ws, size_t ws_size,
                              hipStream_t stream) {
    const float* x  = (const float*)d_in[0];
    const int*   ei = (const int*)d_in[1];
    const float* ev = (const float*)d_in[2];
    const float* W1 = (const float*)d_in[3];
    const float* b1 = (const float*)d_in[4];
    const float* W2 = (const float*)d_in[5];
    const float* b2 = (const float*)d_in[6];
    float* out = (float*)d_out;

    char* ws = (char*)d_ws;
    size_t off = 0;
    auto alloc = [&](size_t bytes) { size_t o = off; off += (bytes + 255) & ~(size_t)255; return o; };
    const size_t ZB  = (size_t)N_NODES * BATCH * F0 * 4;      // 10.24 MB per z buffer
    size_t o_z0  = alloc(ZB);
    size_t o_z11 = alloc(ZB);
    size_t o_z12 = alloc(ZB);
    size_t o_z21 = alloc(ZB);
    size_t o_z22 = alloc(ZB);
    size_t o_h   = alloc((size_t)N_NODES * BATCH * F1 * 4);   // 20.48 MB
    size_t o_ccol = alloc((size_t)NG * N_EDGES * 4);
    size_t o_cval = alloc((size_t)NG * N_EDGES * 4);
    size_t o_rs   = alloc((size_t)NG * (N_NODES + 1) * 4);
    size_t o_wc   = alloc((size_t)5 * 64 * 128 * 4);
    size_t o_zero = off;                                      // zeroed region starts here
    size_t o_cnt    = alloc((size_t)NG * N_NODES * 4);
    size_t o_cursor = alloc((size_t)NG * N_NODES * 4);
    size_t o_r      = alloc((size_t)2 * NG * N_NODES * 4);    // r1[2][N] then r2[2][N]
    size_t o_q      = alloc((size_t)4 * 512 * 4);
    size_t zero_bytes = off - o_zero;

    float* z0  = (float*)(ws + o_z0);
    float* z11 = (float*)(ws + o_z11);
    float* z12 = (float*)(ws + o_z12);
    float* z21 = (float*)(ws + o_z21);
    float* z22 = (float*)(ws + o_z22);
    float* h   = (float*)(ws + o_h);
    int*   ccol = (int*)(ws + o_ccol);
    float* cval = (float*)(ws + o_cval);
    int*   rs   = (int*)(ws + o_rs);
    float* Wc   = (float*)(ws + o_wc);
    int*   cnt    = (int*)(ws + o_cnt);
    int*   cursor = (int*)(ws + o_cursor);
    float* r1   = (float*)(ws + o_r);
    float* r2   = r1 + 2 * N_NODES;
    float* q    = (float*)(ws + o_q);

    hipMemsetAsync(ws + o_zero, 0, zero_bytes, stream);
    hipMemsetAsync(out, 0, 512 * sizeof(float), stream);

    hist_kernel   <<<2500, 256, 0, stream>>>(ei, cnt);
    prefix_kernel <<<2,    256, 0, stream>>>(cnt, rs);
    scatter_kernel<<<2500, 256, 0, stream>>>(ei, ev, rs, cursor, ccol, cval);
    transpose_kernel<<<10000, 256, 0, stream>>>(x, z0);
    prep_w_kernel <<<160,  256, 0, stream>>>(W1, Wc);
    spmm_kernel   <<<2 * N_NODES, 256, 0, stream>>>(ccol, cval, rs, z0,  z0,  z11, z21);
    spmm_kernel   <<<2 * N_NODES, 256, 0, stream>>>(ccol, cval, rs, z11, z21, z12, z22);
    gemm_kernel   <<<1250, 256, 0, stream>>>(z0, z11, z12, z21, z22, Wc, b1, h);
    r1_kernel     <<<2500, 256, 0, stream>>>(ei, ev, r1);
    r2_kernel     <<<2500, 256, 0, stream>>>(ei, ev, r1, r2);
    q_kernel      <<<157,  512, 0, stream>>>(h, r1, r2, q);
    final_kernel  <<<8,    512, 0, stream>>>(h, q, W2, b2, out);
}

// Round 3
// 312.654 us; speedup vs baseline: 1.6800x; 1.2877x over previous
//
#include <hip/hip_runtime.h>

#define N_NODES 10000
#define N_EDGES 320000
#define NG      2
#define BATCH   4
#define F0      64
#define F1      128
#define F2      128
// z layout: [n][B*F0=256] bf16 (512 B/node). h: [m=n*4+b][128] fp32.

typedef __bf16 bf16x8 __attribute__((ext_vector_type(8)));
typedef float  f32x4  __attribute__((ext_vector_type(4)));

__device__ __forceinline__ unsigned short f2bf(float x) {
    unsigned int u = __float_as_uint(x);
    unsigned int r = (u + 0x7fff + ((u >> 16) & 1)) >> 16;   // RNE
    return (unsigned short)r;
}
__device__ __forceinline__ float bflo(unsigned int u) { return __uint_as_float(u << 16); }
__device__ __forceinline__ float bfhi(unsigned int u) { return __uint_as_float(u & 0xffff0000u); }

// ---------------------------------------------------------------- CSR build
__global__ void hist_kernel(const int* __restrict__ ei, int* __restrict__ cnt) {
    int j = blockIdx.x * 256 + threadIdx.x;
    if (j >= NG * N_EDGES) return;
    int e = j / N_EDGES, t = j - e * N_EDGES;
    int r = ei[e * 2 * N_EDGES + t];
    atomicAdd(&cnt[e * N_NODES + r], 1);
}

__global__ void prefix_kernel(const int* __restrict__ cnt, int* __restrict__ row_start) {
    __shared__ int buf[256];
    __shared__ int carry;
    int e = blockIdx.x;
    int t = threadIdx.x;
    if (t == 0) carry = 0;
    __syncthreads();
    for (int base = 0; base < N_NODES; base += 256) {
        int i = base + t;
        int v = (i < N_NODES) ? cnt[e * N_NODES + i] : 0;
        buf[t] = v;
        __syncthreads();
        for (int off = 1; off < 256; off <<= 1) {
            int x = (t >= off) ? buf[t - off] : 0;
            __syncthreads();
            buf[t] += x;
            __syncthreads();
        }
        int incl = buf[t];
        int excl = incl - v;
        if (i < N_NODES) row_start[e * (N_NODES + 1) + i] = carry + excl;
        __syncthreads();
        if (t == 255) carry += incl;
        __syncthreads();
    }
    if (t == 0) row_start[e * (N_NODES + 1) + N_NODES] = carry;
}

__global__ void scatter_kernel(const int* __restrict__ ei, const float* __restrict__ ev,
                               const int* __restrict__ row_start, int* __restrict__ cursor,
                               int* __restrict__ ccol, float* __restrict__ cval) {
    int j = blockIdx.x * 256 + threadIdx.x;
    if (j >= NG * N_EDGES) return;
    int e = j / N_EDGES, t = j - e * N_EDGES;
    int r = ei[e * 2 * N_EDGES + t];
    int c = ei[e * 2 * N_EDGES + N_EDGES + t];
    float v = ev[e * N_EDGES + t];
    int pos = row_start[e * (N_NODES + 1) + r] + atomicAdd(&cursor[e * N_NODES + r], 1);
    ccol[e * N_EDGES + pos] = c;
    cval[e * N_EDGES + pos] = v;
}

// ---------------------------------------------------------------- x[B,N,F0] fp32 -> z0[N,256] bf16
__global__ void transpose_kernel(const float* __restrict__ x, unsigned short* __restrict__ z0) {
    int idx = blockIdx.x * 256 + threadIdx.x;   // covers N*B*F0 exactly
    int n = idx >> 8, rem = idx & 255, b = rem >> 6, f = rem & 63;
    z0[idx] = f2bf(x[b * (N_NODES * F0) + n * F0 + f]);
}

// ---------------------------------------------------------------- SpMM (CSR, bf16 gather, fp32 acc)
// block = row (node, gso); 4 waves; each wave-half (32 lanes) covers one edge's
// 256-elem vector with 16 B loads (8 bf16/lane). 8 edges/round/block, unroll x2.
__global__ __launch_bounds__(256) void spmm_kernel(
        const int* __restrict__ ccol, const float* __restrict__ cval,
        const int* __restrict__ row_start,
        const unsigned short* __restrict__ zin0, const unsigned short* __restrict__ zin1,
        unsigned short* __restrict__ zout0, unsigned short* __restrict__ zout1) {
    __shared__ float red[3][256];
    int blk = blockIdx.x;
    int e = (blk >= N_NODES) ? 1 : 0;
    int i = blk - e * N_NODES;
    const unsigned short* zin = e ? zin1 : zin0;
    unsigned short* zout = e ? zout1 : zout0;
    const int*   cc = ccol + e * N_EDGES;
    const float* cv = cval + e * N_EDGES;
    int s    = row_start[e * (N_NODES + 1) + i];
    int send = row_start[e * (N_NODES + 1) + i + 1];
    int t = threadIdx.x;
    int w = t >> 6, l = t & 63;
    int hf = l >> 5, li = l & 31;
    float acc[8];
    #pragma unroll
    for (int j = 0; j < 8; ++j) acc[j] = 0.f;

    int p = s + (w << 1) + hf;
    for (; p + 8 < send; p += 16) {
        int c0 = cc[p];     float v0 = cv[p];
        int c1 = cc[p + 8]; float v1 = cv[p + 8];
        uint4 za = *(const uint4*)&zin[c0 * 256 + li * 8];
        uint4 zb = *(const uint4*)&zin[c1 * 256 + li * 8];
        acc[0] += v0 * bflo(za.x) + v1 * bflo(zb.x);
        acc[1] += v0 * bfhi(za.x) + v1 * bfhi(zb.x);
        acc[2] += v0 * bflo(za.y) + v1 * bflo(zb.y);
        acc[3] += v0 * bfhi(za.y) + v1 * bfhi(zb.y);
        acc[4] += v0 * bflo(za.z) + v1 * bflo(zb.z);
        acc[5] += v0 * bfhi(za.z) + v1 * bfhi(zb.z);
        acc[6] += v0 * bflo(za.w) + v1 * bflo(zb.w);
        acc[7] += v0 * bfhi(za.w) + v1 * bfhi(zb.w);
    }
    for (; p < send; p += 8) {
        int c0 = cc[p]; float v0 = cv[p];
        uint4 za = *(const uint4*)&zin[c0 * 256 + li * 8];
        acc[0] += v0 * bflo(za.x); acc[1] += v0 * bfhi(za.x);
        acc[2] += v0 * bflo(za.y); acc[3] += v0 * bfhi(za.y);
        acc[4] += v0 * bflo(za.z); acc[5] += v0 * bfhi(za.z);
        acc[6] += v0 * bflo(za.w); acc[7] += v0 * bfhi(za.w);
    }
    // combine lane halves (both hold elems li*8..li*8+7)
    #pragma unroll
    for (int j = 0; j < 8; ++j) acc[j] += __shfl_xor(acc[j], 32);
    if (w && hf == 0) {
        #pragma unroll
        for (int j = 0; j < 8; ++j) red[w - 1][li * 8 + j] = acc[j];
    }
    __syncthreads();
    if (w == 0 && hf == 0) {
        uint4 o;
        unsigned int r[8];
        #pragma unroll
        for (int j = 0; j < 8; ++j) {
            float v = acc[j] + red[0][li * 8 + j] + red[1][li * 8 + j] + red[2][li * 8 + j];
            r[j] = f2bf(v);
        }
        o.x = r[0] | (r[1] << 16);
        o.y = r[2] | (r[3] << 16);
        o.z = r[4] | (r[5] << 16);
        o.w = r[6] | (r[7] << 16);
        *(uint4*)&zout[i * 256 + li * 8] = o;
    }
}

// ---------------------------------------------------------------- weight prep
// Bsw[s][kk][nt][lane][j] bf16 = Wc_s[k=kk*32+(lane>>4)*8+j][n=nt*16+(lane&15)]
// Wc_s: s=0: W1[0,0]+W1[1,0]; s=1: W1[0,1]; s=2: W1[0,2]; s=3: W1[1,1]; s=4: W1[1,2]
__global__ void prep_w_kernel(const float* __restrict__ W1, unsigned short* __restrict__ Bsw) {
    int idx = blockIdx.x * 256 + threadIdx.x;   // 160*256 = 40960 exactly
    int j    = idx & 7;
    int lane = (idx >> 3) & 63;
    int nt   = (idx >> 9) & 7;
    int kk   = (idx >> 12) & 1;
    int s    = idx >> 13;
    int k = kk * 32 + ((lane >> 4) << 3) + j;
    int n = nt * 16 + (lane & 15);
    int wi = k * 128 + n;
    float v;
    if (s == 0)      v = W1[0 * 8192 + wi] + W1[3 * 8192 + wi];
    else if (s == 1) v = W1[1 * 8192 + wi];
    else if (s == 2) v = W1[2 * 8192 + wi];
    else if (s == 3) v = W1[4 * 8192 + wi];
    else             v = W1[5 * 8192 + wi];
    Bsw[idx] = f2bf(v);
}

// ---------------------------------------------------------------- layer-1 MFMA GEMM (no LDS)
// h[m,0:128] = b1 + sum_s z_s[m,0:64] @ Wc[s];  M = 40000, block=64 rows, wave=16 rows x 128 cols
__global__ __launch_bounds__(256) void gemm_kernel(
        const unsigned short* __restrict__ z0,  const unsigned short* __restrict__ z11,
        const unsigned short* __restrict__ z12, const unsigned short* __restrict__ z21,
        const unsigned short* __restrict__ z22, const unsigned short* __restrict__ Bsw,
        const float* __restrict__ b1,  float* __restrict__ h) {
    int t = threadIdx.x;
    int w = t >> 6, l = t & 63;
    int m0 = blockIdx.x * 64 + w * 16;
    int am  = l & 15;           // A row within tile
    int ak8 = (l >> 4) << 3;    // A k-offset within 32-wide K step
    const unsigned short* Z[5] = { z0, z11, z12, z21, z22 };
    f32x4 acc[8];
    #pragma unroll
    for (int nt = 0; nt < 8; ++nt) acc[nt] = (f32x4){0.f, 0.f, 0.f, 0.f};

    #pragma unroll
    for (int s = 0; s < 5; ++s) {
        const unsigned short* A = Z[s] + (m0 + am) * 64;
        #pragma unroll
        for (int kk = 0; kk < 2; ++kk) {
            bf16x8 a = *(const bf16x8*)(A + kk * 32 + ak8);
            const unsigned short* B = Bsw + (((s * 2 + kk) * 8) * 64 + l) * 8;
            #pragma unroll
            for (int nt = 0; nt < 8; ++nt) {
                bf16x8 b = *(const bf16x8*)(B + nt * 512);
                acc[nt] = __builtin_amdgcn_mfma_f32_16x16x32_bf16(a, b, acc[nt], 0, 0, 0);
            }
        }
    }
    // C/D: lane holds D[m = (l>>4)*4 + reg][n = l&15]
    int mrow = m0 + ((l >> 4) << 2);
    int ncol = l & 15;
    #pragma unroll
    for (int nt = 0; nt < 8; ++nt) {
        int n = nt * 16 + ncol;
        float bias = b1[n];
        #pragma unroll
        for (int r = 0; r < 4; ++r) {
            h[(mrow + r) * 128 + n] = acc[nt][r] + bias;
        }
    }
}

// ---------------------------------------------------------------- layer-2 row-0 propagation vectors
__global__ void r1_kernel(const int* __restrict__ ei, const float* __restrict__ ev,
                          float* __restrict__ r1) {
    int j = blockIdx.x * 256 + threadIdx.x;
    if (j >= NG * N_EDGES) return;
    int e = j / N_EDGES, t = j - e * N_EDGES;
    if (ei[e * 2 * N_EDGES + t] == 0) {
        int c = ei[e * 2 * N_EDGES + N_EDGES + t];
        atomicAdd(&r1[e * N_NODES + c], ev[e * N_EDGES + t]);
    }
}

__global__ void r2_kernel(const int* __restrict__ ei, const float* __restrict__ ev,
                          const float* __restrict__ r1, float* __restrict__ r2) {
    int j = blockIdx.x * 256 + threadIdx.x;
    if (j >= NG * N_EDGES) return;
    int e = j / N_EDGES, t = j - e * N_EDGES;
    float w = r1[e * N_NODES + ei[e * 2 * N_EDGES + t]];
    if (w != 0.f) {
        int c = ei[e * 2 * N_EDGES + N_EDGES + t];
        atomicAdd(&r2[e * N_NODES + c], w * ev[e * N_EDGES + t]);
    }
}

// q[ek][b*128+f1] = sum_n r_ek[n] * h[n,b,f1]
__global__ void q_kernel(const float* __restrict__ h, const float* __restrict__ r1,
                         const float* __restrict__ r2, float* __restrict__ q) {
    int t = threadIdx.x;                 // 512 threads = (b,f1)
    int n0 = blockIdx.x * 64;
    int n1 = n0 + 64; if (n1 > N_NODES) n1 = N_NODES;
    float a0 = 0.f, a1 = 0.f, a2 = 0.f, a3 = 0.f;
    for (int n = n0; n < n1; ++n) {
        float w0 = r1[n];
        float w1 = r2[n];
        float w2 = r1[N_NODES + n];
        float w3 = r2[N_NODES + n];
        if (w0 == 0.f && w1 == 0.f && w2 == 0.f && w3 == 0.f) continue;
        float hv = h[n * 512 + t];
        a0 += w0 * hv; a1 += w1 * hv; a2 += w2 * hv; a3 += w3 * hv;
    }
    if (a0 != 0.f) atomicAdd(&q[0 * 512 + t], a0);
    if (a1 != 0.f) atomicAdd(&q[1 * 512 + t], a1);
    if (a2 != 0.f) atomicAdd(&q[2 * 512 + t], a2);
    if (a3 != 0.f) atomicAdd(&q[3 * 512 + t], a3);
}

// out[b,f2] = b2 + h[0,b,:]·(W2[0,0]+W2[1,0]) + q0·W2[0,1] + q1·W2[0,2] + q2·W2[1,1] + q3·W2[1,2]
__global__ void final_kernel(const float* __restrict__ h, const float* __restrict__ q,
                             const float* __restrict__ W2, const float* __restrict__ b2,
                             float* __restrict__ out) {
    int t = threadIdx.x;               // 512
    int b = t >> 7, f2 = t & 127;
    int f1_0 = blockIdx.x * 16;        // 8 blocks x 16 f1 each
    float acc = (blockIdx.x == 0) ? b2[f2] : 0.f;
    for (int f1 = f1_0; f1 < f1_0 + 16; ++f1) {
        int wi = f1 * 128 + f2;
        float w00 = W2[0 * 16384 + wi] + W2[3 * 16384 + wi];
        acc += h[b * 128 + f1] * w00;
        acc += q[0 * 512 + b * 128 + f1] * W2[1 * 16384 + wi];
        acc += q[1 * 512 + b * 128 + f1] * W2[2 * 16384 + wi];
        acc += q[2 * 512 + b * 128 + f1] * W2[4 * 16384 + wi];
        acc += q[3 * 512 + b * 128 + f1] * W2[5 * 16384 + wi];
    }
    atomicAdd(&out[b * 128 + f2], acc);
}

// ----------------------------------------------------------------
extern "C" void kernel_launch(void* const* d_in, const int* in_sizes, int n_in,
                              void* d_out, int out_size, void* d_ws, size_t ws_size,
                              hipStream_t stream) {
    const float* x  = (const float*)d_in[0];
    const int*   ei = (const int*)d_in[1];
    const float* ev = (const float*)d_in[2];
    const float* W1 = (const float*)d_in[3];
    const float* b1 = (const float*)d_in[4];
    const float* W2 = (const float*)d_in[5];
    const float* b2 = (const float*)d_in[6];
    float* out = (float*)d_out;

    char* ws = (char*)d_ws;
    size_t off = 0;
    auto alloc = [&](size_t bytes) { size_t o = off; off += (bytes + 255) & ~(size_t)255; return o; };
    const size_t ZB  = (size_t)N_NODES * BATCH * F0 * 2;      // 5.12 MB per bf16 z buffer
    size_t o_z0  = alloc(ZB);
    size_t o_z11 = alloc(ZB);
    size_t o_z12 = alloc(ZB);
    size_t o_z21 = alloc(ZB);
    size_t o_z22 = alloc(ZB);
    size_t o_h   = alloc((size_t)N_NODES * BATCH * F1 * 4);   // 20.48 MB fp32
    size_t o_ccol = alloc((size_t)NG * N_EDGES * 4);
    size_t o_cval = alloc((size_t)NG * N_EDGES * 4);
    size_t o_rs   = alloc((size_t)NG * (N_NODES + 1) * 4);
    size_t o_bsw  = alloc((size_t)5 * 2 * 8 * 64 * 8 * 2);    // 80 KB bf16 swizzled W
    size_t o_zero = off;                                      // zeroed region starts here
    size_t o_cnt    = alloc((size_t)NG * N_NODES * 4);
    size_t o_cursor = alloc((size_t)NG * N_NODES * 4);
    size_t o_r      = alloc((size_t)2 * NG * N_NODES * 4);    // r1[2][N] then r2[2][N]
    size_t o_q      = alloc((size_t)4 * 512 * 4);
    size_t zero_bytes = off - o_zero;

    unsigned short* z0  = (unsigned short*)(ws + o_z0);
    unsigned short* z11 = (unsigned short*)(ws + o_z11);
    unsigned short* z12 = (unsigned short*)(ws + o_z12);
    unsigned short* z21 = (unsigned short*)(ws + o_z21);
    unsigned short* z22 = (unsigned short*)(ws + o_z22);
    float* h   = (float*)(ws + o_h);
    int*   ccol = (int*)(ws + o_ccol);
    float* cval = (float*)(ws + o_cval);
    int*   rs   = (int*)(ws + o_rs);
    unsigned short* Bsw = (unsigned short*)(ws + o_bsw);
    int*   cnt    = (int*)(ws + o_cnt);
    int*   cursor = (int*)(ws + o_cursor);
    float* r1   = (float*)(ws + o_r);
    float* r2   = r1 + 2 * N_NODES;
    float* q    = (float*)(ws + o_q);

    hipMemsetAsync(ws + o_zero, 0, zero_bytes, stream);
    hipMemsetAsync(out, 0, 512 * sizeof(float), stream);

    hist_kernel   <<<2500, 256, 0, stream>>>(ei, cnt);
    prefix_kernel <<<2,    256, 0, stream>>>(cnt, rs);
    scatter_kernel<<<2500, 256, 0, stream>>>(ei, ev, rs, cursor, ccol, cval);
    transpose_kernel<<<10000, 256, 0, stream>>>(x, z0);
    prep_w_kernel <<<160,  256, 0, stream>>>(W1, Bsw);
    spmm_kernel   <<<2 * N_NODES, 256, 0, stream>>>(ccol, cval, rs, z0,  z0,  z11, z21);
    spmm_kernel   <<<2 * N_NODES, 256, 0, stream>>>(ccol, cval, rs, z11, z21, z12, z22);
    gemm_kernel   <<<625, 256, 0, stream>>>(z0, z11, z12, z21, z22, Bsw, b1, h);
    r1_kernel     <<<2500, 256, 0, stream>>>(ei, ev, r1);
    r2_kernel     <<<2500, 256, 0, stream>>>(ei, ev, r1, r2);
    q_kernel      <<<157,  512, 0, stream>>>(h, r1, r2, q);
    final_kernel  <<<8,    512, 0, stream>>>(h, q, W2, b2, out);
}

// Round 4
// 237.011 us; speedup vs baseline: 2.2161x; 1.3192x over previous
//
#include <hip/hip_runtime.h>

#define N_NODES 10000
#define N_EDGES 320000
#define NG      2
#define BATCH   4
#define F0      64
#define F1      128
#define F2      128
// z layout: [n][B*F0=256] bf16 (512 B/node). h: [m=n*4+b][128] fp32.

typedef __bf16 bf16x8 __attribute__((ext_vector_type(8)));
typedef float  f32x4  __attribute__((ext_vector_type(4)));

__device__ __forceinline__ unsigned short f2bf(float x) {
    unsigned int u = __float_as_uint(x);
    unsigned int r = (u + 0x7fff + ((u >> 16) & 1)) >> 16;   // RNE
    return (unsigned short)r;
}
__device__ __forceinline__ float bflo(unsigned int u) { return __uint_as_float(u << 16); }
__device__ __forceinline__ float bfhi(unsigned int u) { return __uint_as_float(u & 0xffff0000u); }

// ---------------------------------------------------------------- CSR build pass 1
// histogram + per-edge slot (return of the atomic) + fused r1 build
__global__ void hist_kernel(const int* __restrict__ ei, const float* __restrict__ ev,
                            int* __restrict__ cnt, int* __restrict__ slot,
                            float* __restrict__ r1) {
    int j = blockIdx.x * 256 + threadIdx.x;
    if (j >= NG * N_EDGES) return;
    int e = j / N_EDGES, t = j - e * N_EDGES;
    int r = ei[e * 2 * N_EDGES + t];
    slot[j] = atomicAdd(&cnt[e * N_NODES + r], 1);
    if (r == 0) {
        int c = ei[e * 2 * N_EDGES + N_EDGES + t];
        atomicAdd(&r1[e * N_NODES + c], ev[e * N_EDGES + t]);
    }
}

// ---------------------------------------------------------------- CSR build pass 2
// block = gso; 1024 threads; 10 elems/thread in regs; wave shfl scan + LDS wave totals
__global__ __launch_bounds__(1024) void prefix_kernel(const int* __restrict__ cnt,
                                                      int* __restrict__ rs) {
    __shared__ int wtot[16];
    int e = blockIdx.x, t = threadIdx.x;
    int lane = t & 63, w = t >> 6;
    int i0 = t * 10;
    int c[10];
    int local = 0;
    #pragma unroll
    for (int j = 0; j < 10; ++j) {
        int i = i0 + j;
        int v = (i < N_NODES) ? cnt[e * N_NODES + i] : 0;
        c[j] = local;                 // exclusive-within-thread prefix
        local += v;
    }
    int inc = local;
    #pragma unroll
    for (int off = 1; off < 64; off <<= 1) {
        int u = __shfl_up(inc, off);
        if (lane >= off) inc += u;
    }
    if (lane == 63) wtot[w] = inc;
    __syncthreads();
    int base = 0;
    for (int k = 0; k < w; ++k) base += wtot[k];
    int excl = base + inc - local;    // exclusive prefix of this thread's chunk
    #pragma unroll
    for (int j = 0; j < 10; ++j) {
        int i = i0 + j;
        if (i < N_NODES) rs[e * (N_NODES + 1) + i] = excl + c[j];
    }
    if (t == 1023) {
        int grand = 0;
        #pragma unroll
        for (int k = 0; k < 16; ++k) grand += wtot[k];
        rs[e * (N_NODES + 1) + N_NODES] = grand;
    }
}

// ---------------------------------------------------------------- CSR build pass 3
// atomic-free scatter of interleaved (col,val); fused r2 build (r1 complete after hist)
__global__ void scatter_kernel(const int* __restrict__ ei, const float* __restrict__ ev,
                               const int* __restrict__ rs, const int* __restrict__ slot,
                               const float* __restrict__ r1,
                               int2* __restrict__ cev, float* __restrict__ r2) {
    int j = blockIdx.x * 256 + threadIdx.x;
    if (j >= NG * N_EDGES) return;
    int e = j / N_EDGES, t = j - e * N_EDGES;
    int r = ei[e * 2 * N_EDGES + t];
    int c = ei[e * 2 * N_EDGES + N_EDGES + t];
    float v = ev[e * N_EDGES + t];
    int pos = rs[e * (N_NODES + 1) + r] + slot[j];
    cev[e * N_EDGES + pos] = make_int2(c, __float_as_int(v));
    float w = r1[e * N_NODES + r];
    if (w != 0.f) atomicAdd(&r2[e * N_NODES + c], w * v);
}

// ---------------------------------------------------------------- x[B,N,F0] fp32 -> z0[N,256] bf16
__global__ void transpose_kernel(const float* __restrict__ x, unsigned short* __restrict__ z0) {
    int idx = blockIdx.x * 256 + threadIdx.x;   // covers N*B*F0 exactly
    int n = idx >> 8, rem = idx & 255, b = rem >> 6, f = rem & 63;
    z0[idx] = f2bf(x[b * (N_NODES * F0) + n * F0 + f]);
}

// ---------------------------------------------------------------- SpMM (CSR, bf16 gather, fp32 acc)
// block = row (node, gso); 4 waves; each wave-half (32 lanes) covers one edge's
// 256-elem vector with 16 B loads (8 bf16/lane). 8 edges/round/block, unroll x2.
__global__ __launch_bounds__(256) void spmm_kernel(
        const int2* __restrict__ cev, const int* __restrict__ rs,
        const unsigned short* __restrict__ zin0, const unsigned short* __restrict__ zin1,
        unsigned short* __restrict__ zout0, unsigned short* __restrict__ zout1) {
    __shared__ float red[3][256];
    int blk = blockIdx.x;
    int e = (blk >= N_NODES) ? 1 : 0;
    int i = blk - e * N_NODES;
    const unsigned short* zin = e ? zin1 : zin0;
    unsigned short* zout = e ? zout1 : zout0;
    const int2* cv = cev + e * N_EDGES;
    int s    = rs[e * (N_NODES + 1) + i];
    int send = rs[e * (N_NODES + 1) + i + 1];
    int t = threadIdx.x;
    int w = t >> 6, l = t & 63;
    int hf = l >> 5, li = l & 31;
    float acc[8];
    #pragma unroll
    for (int j = 0; j < 8; ++j) acc[j] = 0.f;

    int p = s + (w << 1) + hf;
    for (; p + 8 < send; p += 16) {
        int2 e0 = cv[p];
        int2 e1 = cv[p + 8];
        int c0 = e0.x; float v0 = __int_as_float(e0.y);
        int c1 = e1.x; float v1 = __int_as_float(e1.y);
        uint4 za = *(const uint4*)&zin[c0 * 256 + li * 8];
        uint4 zb = *(const uint4*)&zin[c1 * 256 + li * 8];
        acc[0] += v0 * bflo(za.x) + v1 * bflo(zb.x);
        acc[1] += v0 * bfhi(za.x) + v1 * bfhi(zb.x);
        acc[2] += v0 * bflo(za.y) + v1 * bflo(zb.y);
        acc[3] += v0 * bfhi(za.y) + v1 * bfhi(zb.y);
        acc[4] += v0 * bflo(za.z) + v1 * bflo(zb.z);
        acc[5] += v0 * bfhi(za.z) + v1 * bfhi(zb.z);
        acc[6] += v0 * bflo(za.w) + v1 * bflo(zb.w);
        acc[7] += v0 * bfhi(za.w) + v1 * bfhi(zb.w);
    }
    for (; p < send; p += 8) {
        int2 e0 = cv[p];
        int c0 = e0.x; float v0 = __int_as_float(e0.y);
        uint4 za = *(const uint4*)&zin[c0 * 256 + li * 8];
        acc[0] += v0 * bflo(za.x); acc[1] += v0 * bfhi(za.x);
        acc[2] += v0 * bflo(za.y); acc[3] += v0 * bfhi(za.y);
        acc[4] += v0 * bflo(za.z); acc[5] += v0 * bfhi(za.z);
        acc[6] += v0 * bflo(za.w); acc[7] += v0 * bfhi(za.w);
    }
    // combine lane halves (both hold elems li*8..li*8+7)
    #pragma unroll
    for (int j = 0; j < 8; ++j) acc[j] += __shfl_xor(acc[j], 32);
    if (w && hf == 0) {
        #pragma unroll
        for (int j = 0; j < 8; ++j) red[w - 1][li * 8 + j] = acc[j];
    }
    __syncthreads();
    if (w == 0 && hf == 0) {
        uint4 o;
        unsigned int r[8];
        #pragma unroll
        for (int j = 0; j < 8; ++j) {
            float v = acc[j] + red[0][li * 8 + j] + red[1][li * 8 + j] + red[2][li * 8 + j];
            r[j] = f2bf(v);
        }
        o.x = r[0] | (r[1] << 16);
        o.y = r[2] | (r[3] << 16);
        o.z = r[4] | (r[5] << 16);
        o.w = r[6] | (r[7] << 16);
        *(uint4*)&zout[i * 256 + li * 8] = o;
    }
}

// ---------------------------------------------------------------- weight prep
// Bsw[s][kk][nt][lane][j] bf16 = Wc_s[k=kk*32+(lane>>4)*8+j][n=nt*16+(lane&15)]
// Wc_s: s=0: W1[0,0]+W1[1,0]; s=1: W1[0,1]; s=2: W1[0,2]; s=3: W1[1,1]; s=4: W1[1,2]
__global__ void prep_w_kernel(const float* __restrict__ W1, unsigned short* __restrict__ Bsw) {
    int idx = blockIdx.x * 256 + threadIdx.x;   // 160*256 = 40960 exactly
    int j    = idx & 7;
    int lane = (idx >> 3) & 63;
    int nt   = (idx >> 9) & 7;
    int kk   = (idx >> 12) & 1;
    int s    = idx >> 13;
    int k = kk * 32 + ((lane >> 4) << 3) + j;
    int n = nt * 16 + (lane & 15);
    int wi = k * 128 + n;
    float v;
    if (s == 0)      v = W1[0 * 8192 + wi] + W1[3 * 8192 + wi];
    else if (s == 1) v = W1[1 * 8192 + wi];
    else if (s == 2) v = W1[2 * 8192 + wi];
    else if (s == 3) v = W1[4 * 8192 + wi];
    else             v = W1[5 * 8192 + wi];
    Bsw[idx] = f2bf(v);
}

// ---------------------------------------------------------------- layer-1 MFMA GEMM (no LDS)
// h[m,0:128] = b1 + sum_s z_s[m,0:64] @ Wc[s];  M = 40000, block=64 rows, wave=16 rows x 128 cols
__global__ __launch_bounds__(256) void gemm_kernel(
        const unsigned short* __restrict__ z0,  const unsigned short* __restrict__ z11,
        const unsigned short* __restrict__ z12, const unsigned short* __restrict__ z21,
        const unsigned short* __restrict__ z22, const unsigned short* __restrict__ Bsw,
        const float* __restrict__ b1,  float* __restrict__ h) {
    int t = threadIdx.x;
    int w = t >> 6, l = t & 63;
    int m0 = blockIdx.x * 64 + w * 16;
    int am  = l & 15;           // A row within tile
    int ak8 = (l >> 4) << 3;    // A k-offset within 32-wide K step
    const unsigned short* Z[5] = { z0, z11, z12, z21, z22 };
    f32x4 acc[8];
    #pragma unroll
    for (int nt = 0; nt < 8; ++nt) acc[nt] = (f32x4){0.f, 0.f, 0.f, 0.f};

    #pragma unroll
    for (int s = 0; s < 5; ++s) {
        const unsigned short* A = Z[s] + (m0 + am) * 64;
        #pragma unroll
        for (int kk = 0; kk < 2; ++kk) {
            bf16x8 a = *(const bf16x8*)(A + kk * 32 + ak8);
            const unsigned short* B = Bsw + (((s * 2 + kk) * 8) * 64 + l) * 8;
            #pragma unroll
            for (int nt = 0; nt < 8; ++nt) {
                bf16x8 b = *(const bf16x8*)(B + nt * 512);
                acc[nt] = __builtin_amdgcn_mfma_f32_16x16x32_bf16(a, b, acc[nt], 0, 0, 0);
            }
        }
    }
    // C/D: lane holds D[m = (l>>4)*4 + reg][n = l&15]
    int mrow = m0 + ((l >> 4) << 2);
    int ncol = l & 15;
    #pragma unroll
    for (int nt = 0; nt < 8; ++nt) {
        int n = nt * 16 + ncol;
        float bias = b1[n];
        #pragma unroll
        for (int r = 0; r < 4; ++r) {
            h[(mrow + r) * 128 + n] = acc[nt][r] + bias;
        }
    }
}

// q[ek][b*128+f1] = sum_n r_ek[n] * h[n,b,f1]
__global__ void q_kernel(const float* __restrict__ h, const float* __restrict__ r1,
                         const float* __restrict__ r2, float* __restrict__ q) {
    int t = threadIdx.x;                 // 512 threads = (b,f1)
    int n0 = blockIdx.x * 64;
    int n1 = n0 + 64; if (n1 > N_NODES) n1 = N_NODES;
    float a0 = 0.f, a1 = 0.f, a2 = 0.f, a3 = 0.f;
    for (int n = n0; n < n1; ++n) {
        float w0 = r1[n];
        float w1 = r2[n];
        float w2 = r1[N_NODES + n];
        float w3 = r2[N_NODES + n];
        if (w0 == 0.f && w1 == 0.f && w2 == 0.f && w3 == 0.f) continue;
        float hv = h[n * 512 + t];
        a0 += w0 * hv; a1 += w1 * hv; a2 += w2 * hv; a3 += w3 * hv;
    }
    if (a0 != 0.f) atomicAdd(&q[0 * 512 + t], a0);
    if (a1 != 0.f) atomicAdd(&q[1 * 512 + t], a1);
    if (a2 != 0.f) atomicAdd(&q[2 * 512 + t], a2);
    if (a3 != 0.f) atomicAdd(&q[3 * 512 + t], a3);
}

// out[b,f2] = b2 + h[0,b,:]·(W2[0,0]+W2[1,0]) + q0·W2[0,1] + q1·W2[0,2] + q2·W2[1,1] + q3·W2[1,2]
__global__ void final_kernel(const float* __restrict__ h, const float* __restrict__ q,
                             const float* __restrict__ W2, const float* __restrict__ b2,
                             float* __restrict__ out) {
    int t = threadIdx.x;               // 512
    int b = t >> 7, f2 = t & 127;
    int f1_0 = blockIdx.x * 16;        // 8 blocks x 16 f1 each
    float acc = (blockIdx.x == 0) ? b2[f2] : 0.f;
    for (int f1 = f1_0; f1 < f1_0 + 16; ++f1) {
        int wi = f1 * 128 + f2;
        float w00 = W2[0 * 16384 + wi] + W2[3 * 16384 + wi];
        acc += h[b * 128 + f1] * w00;
        acc += q[0 * 512 + b * 128 + f1] * W2[1 * 16384 + wi];
        acc += q[1 * 512 + b * 128 + f1] * W2[2 * 16384 + wi];
        acc += q[2 * 512 + b * 128 + f1] * W2[4 * 16384 + wi];
        acc += q[3 * 512 + b * 128 + f1] * W2[5 * 16384 + wi];
    }
    atomicAdd(&out[b * 128 + f2], acc);
}

// ----------------------------------------------------------------
extern "C" void kernel_launch(void* const* d_in, const int* in_sizes, int n_in,
                              void* d_out, int out_size, void* d_ws, size_t ws_size,
                              hipStream_t stream) {
    const float* x  = (const float*)d_in[0];
    const int*   ei = (const int*)d_in[1];
    const float* ev = (const float*)d_in[2];
    const float* W1 = (const float*)d_in[3];
    const float* b1 = (const float*)d_in[4];
    const float* W2 = (const float*)d_in[5];
    const float* b2 = (const float*)d_in[6];
    float* out = (float*)d_out;

    char* ws = (char*)d_ws;
    size_t off = 0;
    auto alloc = [&](size_t bytes) { size_t o = off; off += (bytes + 255) & ~(size_t)255; return o; };
    const size_t ZB  = (size_t)N_NODES * BATCH * F0 * 2;      // 5.12 MB per bf16 z buffer
    size_t o_z0  = alloc(ZB);
    size_t o_z11 = alloc(ZB);
    size_t o_z12 = alloc(ZB);
    size_t o_z21 = alloc(ZB);
    size_t o_z22 = alloc(ZB);
    size_t o_h   = alloc((size_t)N_NODES * BATCH * F1 * 4);   // 20.48 MB fp32
    size_t o_cev  = alloc((size_t)NG * N_EDGES * 8);          // interleaved (col, val)
    size_t o_slot = alloc((size_t)NG * N_EDGES * 4);
    size_t o_rs   = alloc((size_t)NG * (N_NODES + 1) * 4);
    size_t o_bsw  = alloc((size_t)5 * 2 * 8 * 64 * 8 * 2);    // 80 KB bf16 swizzled W
    size_t o_zero = off;                                      // zeroed region starts here
    size_t o_cnt    = alloc((size_t)NG * N_NODES * 4);
    size_t o_r      = alloc((size_t)2 * NG * N_NODES * 4);    // r1[2][N] then r2[2][N]
    size_t o_q      = alloc((size_t)4 * 512 * 4);
    size_t zero_bytes = off - o_zero;

    unsigned short* z0  = (unsigned short*)(ws + o_z0);
    unsigned short* z11 = (unsigned short*)(ws + o_z11);
    unsigned short* z12 = (unsigned short*)(ws + o_z12);
    unsigned short* z21 = (unsigned short*)(ws + o_z21);
    unsigned short* z22 = (unsigned short*)(ws + o_z22);
    float* h   = (float*)(ws + o_h);
    int2*  cev  = (int2*)(ws + o_cev);
    int*   slot = (int*)(ws + o_slot);
    int*   rs   = (int*)(ws + o_rs);
    unsigned short* Bsw = (unsigned short*)(ws + o_bsw);
    int*   cnt  = (int*)(ws + o_cnt);
    float* r1   = (float*)(ws + o_r);
    float* r2   = r1 + 2 * N_NODES;
    float* q    = (float*)(ws + o_q);

    hipMemsetAsync(ws + o_zero, 0, zero_bytes, stream);
    hipMemsetAsync(out, 0, 512 * sizeof(float), stream);

    hist_kernel   <<<2500, 256, 0, stream>>>(ei, ev, cnt, slot, r1);
    prefix_kernel <<<2,   1024, 0, stream>>>(cnt, rs);
    scatter_kernel<<<2500, 256, 0, stream>>>(ei, ev, rs, slot, r1, cev, r2);
    transpose_kernel<<<10000, 256, 0, stream>>>(x, z0);
    prep_w_kernel <<<160,  256, 0, stream>>>(W1, Bsw);
    spmm_kernel   <<<2 * N_NODES, 256, 0, stream>>>(cev, rs, z0,  z0,  z11, z21);
    spmm_kernel   <<<2 * N_NODES, 256, 0, stream>>>(cev, rs, z11, z21, z12, z22);
    gemm_kernel   <<<625, 256, 0, stream>>>(z0, z11, z12, z21, z22, Bsw, b1, h);
    q_kernel      <<<157,  512, 0, stream>>>(h, r1, r2, q);
    final_kernel  <<<8,    512, 0, stream>>>(h, q, W2, b2, out);
}

// Round 5
// 230.678 us; speedup vs baseline: 2.2770x; 1.0275x over previous
//
#include <hip/hip_runtime.h>

#define N_NODES 10000
#define N_EDGES 320000
#define NG      2
#define BATCH   4
#define F0      64
#define F1      128
#define F2      128
// z layout: [n][B*F0=256] bf16 (512 B/node). h: [m=n*4+b][128] fp32.

typedef __bf16 bf16x8 __attribute__((ext_vector_type(8)));
typedef float  f32x4  __attribute__((ext_vector_type(4)));

__device__ __forceinline__ unsigned short f2bf(float x) {
    unsigned int u = __float_as_uint(x);
    unsigned int r = (u + 0x7fff + ((u >> 16) & 1)) >> 16;   // RNE
    return (unsigned short)r;
}
__device__ __forceinline__ float bflo(unsigned int u) { return __uint_as_float(u << 16); }
__device__ __forceinline__ float bfhi(unsigned int u) { return __uint_as_float(u & 0xffff0000u); }

// ---------------------------------------------------------------- CSR build pass 1
// histogram + per-edge slot (return of the atomic) + fused r1 build
__global__ void hist_kernel(const int* __restrict__ ei, const float* __restrict__ ev,
                            int* __restrict__ cnt, int* __restrict__ slot,
                            float* __restrict__ r1) {
    int j = blockIdx.x * 256 + threadIdx.x;
    if (j >= NG * N_EDGES) return;
    int e = j / N_EDGES, t = j - e * N_EDGES;
    int r = ei[e * 2 * N_EDGES + t];
    slot[j] = atomicAdd(&cnt[e * N_NODES + r], 1);
    if (r == 0) {
        int c = ei[e * 2 * N_EDGES + N_EDGES + t];
        atomicAdd(&r1[e * N_NODES + c], ev[e * N_EDGES + t]);
    }
}

// ---------------------------------------------------------------- CSR build pass 2
// block = gso; 1024 threads; 10 elems/thread in regs; wave shfl scan + LDS wave totals
__global__ __launch_bounds__(1024) void prefix_kernel(const int* __restrict__ cnt,
                                                      int* __restrict__ rs) {
    __shared__ int wtot[16];
    int e = blockIdx.x, t = threadIdx.x;
    int lane = t & 63, w = t >> 6;
    int i0 = t * 10;
    int c[10];
    int local = 0;
    #pragma unroll
    for (int j = 0; j < 10; ++j) {
        int i = i0 + j;
        int v = (i < N_NODES) ? cnt[e * N_NODES + i] : 0;
        c[j] = local;                 // exclusive-within-thread prefix
        local += v;
    }
    int inc = local;
    #pragma unroll
    for (int off = 1; off < 64; off <<= 1) {
        int u = __shfl_up(inc, off);
        if (lane >= off) inc += u;
    }
    if (lane == 63) wtot[w] = inc;
    __syncthreads();
    int base = 0;
    for (int k = 0; k < w; ++k) base += wtot[k];
    int excl = base + inc - local;    // exclusive prefix of this thread's chunk
    #pragma unroll
    for (int j = 0; j < 10; ++j) {
        int i = i0 + j;
        if (i < N_NODES) rs[e * (N_NODES + 1) + i] = excl + c[j];
    }
    if (t == 1023) {
        int grand = 0;
        #pragma unroll
        for (int k = 0; k < 16; ++k) grand += wtot[k];
        rs[e * (N_NODES + 1) + N_NODES] = grand;
    }
}

// ---------------------------------------------------------------- CSR build pass 3
// atomic-free scatter of interleaved (col,val); fused r2 build (r1 complete after hist)
__global__ void scatter_kernel(const int* __restrict__ ei, const float* __restrict__ ev,
                               const int* __restrict__ rs, const int* __restrict__ slot,
                               const float* __restrict__ r1,
                               int2* __restrict__ cev, float* __restrict__ r2) {
    int j = blockIdx.x * 256 + threadIdx.x;
    if (j >= NG * N_EDGES) return;
    int e = j / N_EDGES, t = j - e * N_EDGES;
    int r = ei[e * 2 * N_EDGES + t];
    int c = ei[e * 2 * N_EDGES + N_EDGES + t];
    float v = ev[e * N_EDGES + t];
    int pos = rs[e * (N_NODES + 1) + r] + slot[j];
    cev[e * N_EDGES + pos] = make_int2(c, __float_as_int(v));
    float w = r1[e * N_NODES + r];
    if (w != 0.f) atomicAdd(&r2[e * N_NODES + c], w * v);
}

// ---------------------------------------------------------------- fused prep:
// blocks [0,10000): x[B,N,F0] fp32 -> z0[N,256] bf16
// blocks [10000,10160): Bsw[s][kk][nt][lane][j] = bf16 Wc_s swizzle
__global__ void prep_kernel(const float* __restrict__ x, unsigned short* __restrict__ z0,
                            const float* __restrict__ W1, unsigned short* __restrict__ Bsw) {
    int blk = blockIdx.x;
    if (blk < 10000) {
        int idx = blk * 256 + threadIdx.x;   // covers N*B*F0 exactly
        int n = idx >> 8, rem = idx & 255, b = rem >> 6, f = rem & 63;
        z0[idx] = f2bf(x[b * (N_NODES * F0) + n * F0 + f]);
    } else {
        int idx = (blk - 10000) * 256 + threadIdx.x;   // 160*256 = 40960 exactly
        int j    = idx & 7;
        int lane = (idx >> 3) & 63;
        int nt   = (idx >> 9) & 7;
        int kk   = (idx >> 12) & 1;
        int s    = idx >> 13;
        int k = kk * 32 + ((lane >> 4) << 3) + j;
        int n = nt * 16 + (lane & 15);
        int wi = k * 128 + n;
        float v;
        if (s == 0)      v = W1[0 * 8192 + wi] + W1[3 * 8192 + wi];
        else if (s == 1) v = W1[1 * 8192 + wi];
        else if (s == 2) v = W1[2 * 8192 + wi];
        else if (s == 3) v = W1[4 * 8192 + wi];
        else             v = W1[5 * 8192 + wi];
        Bsw[idx] = f2bf(v);
    }
}

// ---------------------------------------------------------------- SpMM (CSR, bf16, fp32 acc)
// wave = one (gso,row); 4 waves/block; lane-half (32 lanes x 8 bf16 = full 512 B
// node vector) per edge slot; 2 slots/wave, unroll x2 -> 4 edges in flight.
// No LDS, no __syncthreads; final combine via shfl_xor(32).
__global__ __launch_bounds__(256) void spmm_kernel(
        const int2* __restrict__ cev, const int* __restrict__ rs,
        const unsigned short* __restrict__ zin0, const unsigned short* __restrict__ zin1,
        unsigned short* __restrict__ zout0, unsigned short* __restrict__ zout1) {
    int t = threadIdx.x;
    int w = t >> 6, l = t & 63;
    int rid = blockIdx.x * 4 + w;            // 0 .. 2*N_NODES-1
    int e = (rid >= N_NODES) ? 1 : 0;
    int i = rid - e * N_NODES;
    const unsigned short* zin = e ? zin1 : zin0;
    unsigned short* zout = e ? zout1 : zout0;
    const int2* cv = cev + e * N_EDGES;
    int s    = rs[e * (N_NODES + 1) + i];
    int send = rs[e * (N_NODES + 1) + i + 1];
    int hf = l >> 5, li = l & 31;
    float acc[8];
    #pragma unroll
    for (int j = 0; j < 8; ++j) acc[j] = 0.f;

    int p = s + hf;
    for (; p + 2 < send; p += 4) {
        int2 e0 = cv[p];
        int2 e1 = cv[p + 2];
        int c0 = e0.x; float v0 = __int_as_float(e0.y);
        int c1 = e1.x; float v1 = __int_as_float(e1.y);
        uint4 za = *(const uint4*)&zin[c0 * 256 + li * 8];
        uint4 zb = *(const uint4*)&zin[c1 * 256 + li * 8];
        acc[0] += v0 * bflo(za.x) + v1 * bflo(zb.x);
        acc[1] += v0 * bfhi(za.x) + v1 * bfhi(zb.x);
        acc[2] += v0 * bflo(za.y) + v1 * bflo(zb.y);
        acc[3] += v0 * bfhi(za.y) + v1 * bfhi(zb.y);
        acc[4] += v0 * bflo(za.z) + v1 * bflo(zb.z);
        acc[5] += v0 * bfhi(za.z) + v1 * bfhi(zb.z);
        acc[6] += v0 * bflo(za.w) + v1 * bflo(zb.w);
        acc[7] += v0 * bfhi(za.w) + v1 * bfhi(zb.w);
    }
    for (; p < send; p += 2) {
        int2 e0 = cv[p];
        int c0 = e0.x; float v0 = __int_as_float(e0.y);
        uint4 za = *(const uint4*)&zin[c0 * 256 + li * 8];
        acc[0] += v0 * bflo(za.x); acc[1] += v0 * bfhi(za.x);
        acc[2] += v0 * bflo(za.y); acc[3] += v0 * bfhi(za.y);
        acc[4] += v0 * bflo(za.z); acc[5] += v0 * bfhi(za.z);
        acc[6] += v0 * bflo(za.w); acc[7] += v0 * bfhi(za.w);
    }
    // combine the two lane-halves (both hold elems li*8..li*8+7)
    #pragma unroll
    for (int j = 0; j < 8; ++j) acc[j] += __shfl_xor(acc[j], 32);
    if (hf == 0) {
        uint4 o;
        unsigned int r[8];
        #pragma unroll
        for (int j = 0; j < 8; ++j) r[j] = f2bf(acc[j]);
        o.x = r[0] | (r[1] << 16);
        o.y = r[2] | (r[3] << 16);
        o.z = r[4] | (r[5] << 16);
        o.w = r[6] | (r[7] << 16);
        *(uint4*)&zout[i * 256 + li * 8] = o;
    }
}

// ---------------------------------------------------------------- layer-1 MFMA GEMM (no LDS)
// h[m,0:128] = b1 + sum_s z_s[m,0:64] @ Wc[s];  M = 40000, block=64 rows, wave=16 rows x 128 cols
__global__ __launch_bounds__(256) void gemm_kernel(
        const unsigned short* __restrict__ z0,  const unsigned short* __restrict__ z11,
        const unsigned short* __restrict__ z12, const unsigned short* __restrict__ z21,
        const unsigned short* __restrict__ z22, const unsigned short* __restrict__ Bsw,
        const float* __restrict__ b1,  float* __restrict__ h) {
    int t = threadIdx.x;
    int w = t >> 6, l = t & 63;
    int m0 = blockIdx.x * 64 + w * 16;
    int am  = l & 15;           // A row within tile
    int ak8 = (l >> 4) << 3;    // A k-offset within 32-wide K step
    const unsigned short* Z[5] = { z0, z11, z12, z21, z22 };
    f32x4 acc[8];
    #pragma unroll
    for (int nt = 0; nt < 8; ++nt) acc[nt] = (f32x4){0.f, 0.f, 0.f, 0.f};

    #pragma unroll
    for (int s = 0; s < 5; ++s) {
        const unsigned short* A = Z[s] + (m0 + am) * 64;
        #pragma unroll
        for (int kk = 0; kk < 2; ++kk) {
            bf16x8 a = *(const bf16x8*)(A + kk * 32 + ak8);
            const unsigned short* B = Bsw + (((s * 2 + kk) * 8) * 64 + l) * 8;
            #pragma unroll
            for (int nt = 0; nt < 8; ++nt) {
                bf16x8 b = *(const bf16x8*)(B + nt * 512);
                acc[nt] = __builtin_amdgcn_mfma_f32_16x16x32_bf16(a, b, acc[nt], 0, 0, 0);
            }
        }
    }
    // C/D: lane holds D[m = (l>>4)*4 + reg][n = l&15]
    int mrow = m0 + ((l >> 4) << 2);
    int ncol = l & 15;
    #pragma unroll
    for (int nt = 0; nt < 8; ++nt) {
        int n = nt * 16 + ncol;
        float bias = b1[n];
        #pragma unroll
        for (int r = 0; r < 4; ++r) {
            h[(mrow + r) * 128 + n] = acc[nt][r] + bias;
        }
    }
}

// q[ek][b*128+f1] = sum_n r_ek[n] * h[n,b,f1]
__global__ void q_kernel(const float* __restrict__ h, const float* __restrict__ r1,
                         const float* __restrict__ r2, float* __restrict__ q) {
    int t = threadIdx.x;                 // 512 threads = (b,f1)
    int n0 = blockIdx.x * 64;
    int n1 = n0 + 64; if (n1 > N_NODES) n1 = N_NODES;
    float a0 = 0.f, a1 = 0.f, a2 = 0.f, a3 = 0.f;
    for (int n = n0; n < n1; ++n) {
        float w0 = r1[n];
        float w1 = r2[n];
        float w2 = r1[N_NODES + n];
        float w3 = r2[N_NODES + n];
        if (w0 == 0.f && w1 == 0.f && w2 == 0.f && w3 == 0.f) continue;
        float hv = h[n * 512 + t];
        a0 += w0 * hv; a1 += w1 * hv; a2 += w2 * hv; a3 += w3 * hv;
    }
    if (a0 != 0.f) atomicAdd(&q[0 * 512 + t], a0);
    if (a1 != 0.f) atomicAdd(&q[1 * 512 + t], a1);
    if (a2 != 0.f) atomicAdd(&q[2 * 512 + t], a2);
    if (a3 != 0.f) atomicAdd(&q[3 * 512 + t], a3);
}

// out[b,f2] = b2 + h[0,b,:]·(W2[0,0]+W2[1,0]) + q0·W2[0,1] + q1·W2[0,2] + q2·W2[1,1] + q3·W2[1,2]
__global__ void final_kernel(const float* __restrict__ h, const float* __restrict__ q,
                             const float* __restrict__ W2, const float* __restrict__ b2,
                             float* __restrict__ out) {
    int t = threadIdx.x;               // 512
    int b = t >> 7, f2 = t & 127;
    int f1_0 = blockIdx.x * 16;        // 8 blocks x 16 f1 each
    float acc = (blockIdx.x == 0) ? b2[f2] : 0.f;
    for (int f1 = f1_0; f1 < f1_0 + 16; ++f1) {
        int wi = f1 * 128 + f2;
        float w00 = W2[0 * 16384 + wi] + W2[3 * 16384 + wi];
        acc += h[b * 128 + f1] * w00;
        acc += q[0 * 512 + b * 128 + f1] * W2[1 * 16384 + wi];
        acc += q[1 * 512 + b * 128 + f1] * W2[2 * 16384 + wi];
        acc += q[2 * 512 + b * 128 + f1] * W2[4 * 16384 + wi];
        acc += q[3 * 512 + b * 128 + f1] * W2[5 * 16384 + wi];
    }
    atomicAdd(&out[b * 128 + f2], acc);
}

// ----------------------------------------------------------------
extern "C" void kernel_launch(void* const* d_in, const int* in_sizes, int n_in,
                              void* d_out, int out_size, void* d_ws, size_t ws_size,
                              hipStream_t stream) {
    const float* x  = (const float*)d_in[0];
    const int*   ei = (const int*)d_in[1];
    const float* ev = (const float*)d_in[2];
    const float* W1 = (const float*)d_in[3];
    const float* b1 = (const float*)d_in[4];
    const float* W2 = (const float*)d_in[5];
    const float* b2 = (const float*)d_in[6];
    float* out = (float*)d_out;

    char* ws = (char*)d_ws;
    size_t off = 0;
    auto alloc = [&](size_t bytes) { size_t o = off; off += (bytes + 255) & ~(size_t)255; return o; };
    const size_t ZB  = (size_t)N_NODES * BATCH * F0 * 2;      // 5.12 MB per bf16 z buffer
    size_t o_z0  = alloc(ZB);
    size_t o_z11 = alloc(ZB);
    size_t o_z12 = alloc(ZB);
    size_t o_z21 = alloc(ZB);
    size_t o_z22 = alloc(ZB);
    size_t o_h   = alloc((size_t)N_NODES * BATCH * F1 * 4);   // 20.48 MB fp32
    size_t o_cev  = alloc((size_t)NG * N_EDGES * 8);          // interleaved (col, val)
    size_t o_slot = alloc((size_t)NG * N_EDGES * 4);
    size_t o_rs   = alloc((size_t)NG * (N_NODES + 1) * 4);
    size_t o_bsw  = alloc((size_t)5 * 2 * 8 * 64 * 8 * 2);    // 80 KB bf16 swizzled W
    size_t o_zero = off;                                      // zeroed region starts here
    size_t o_cnt    = alloc((size_t)NG * N_NODES * 4);
    size_t o_r      = alloc((size_t)2 * NG * N_NODES * 4);    // r1[2][N] then r2[2][N]
    size_t o_q      = alloc((size_t)4 * 512 * 4);
    size_t zero_bytes = off - o_zero;

    unsigned short* z0  = (unsigned short*)(ws + o_z0);
    unsigned short* z11 = (unsigned short*)(ws + o_z11);
    unsigned short* z12 = (unsigned short*)(ws + o_z12);
    unsigned short* z21 = (unsigned short*)(ws + o_z21);
    unsigned short* z22 = (unsigned short*)(ws + o_z22);
    float* h   = (float*)(ws + o_h);
    int2*  cev  = (int2*)(ws + o_cev);
    int*   slot = (int*)(ws + o_slot);
    int*   rs   = (int*)(ws + o_rs);
    unsigned short* Bsw = (unsigned short*)(ws + o_bsw);
    int*   cnt  = (int*)(ws + o_cnt);
    float* r1   = (float*)(ws + o_r);
    float* r2   = r1 + 2 * N_NODES;
    float* q    = (float*)(ws + o_q);

    hipMemsetAsync(ws + o_zero, 0, zero_bytes, stream);
    hipMemsetAsync(out, 0, 512 * sizeof(float), stream);

    hist_kernel   <<<2500, 256, 0, stream>>>(ei, ev, cnt, slot, r1);
    prefix_kernel <<<2,   1024, 0, stream>>>(cnt, rs);
    scatter_kernel<<<2500, 256, 0, stream>>>(ei, ev, rs, slot, r1, cev, r2);
    prep_kernel   <<<10160, 256, 0, stream>>>(x, z0, W1, Bsw);
    spmm_kernel   <<<(2 * N_NODES) / 4, 256, 0, stream>>>(cev, rs, z0,  z0,  z11, z21);
    spmm_kernel   <<<(2 * N_NODES) / 4, 256, 0, stream>>>(cev, rs, z11, z21, z12, z22);
    gemm_kernel   <<<625, 256, 0, stream>>>(z0, z11, z12, z21, z22, Bsw, b1, h);
    q_kernel      <<<157,  512, 0, stream>>>(h, r1, r2, q);
    final_kernel  <<<8,    512, 0, stream>>>(h, q, W2, b2, out);
}

// Round 6
// 225.674 us; speedup vs baseline: 2.3275x; 1.0222x over previous
//
#include <hip/hip_runtime.h>

#define N_NODES 10000
#define N_EDGES 320000
#define NG      2
#define BATCH   4
#define F0      64
#define F1      128
#define F2      128
// z layout: [node][B*F0=256] bf16 (node-indexed, 512 B/node).
// hA layout: [a][B][F1] fp32, compacted over active list (a < nact).

typedef __bf16 bf16x8 __attribute__((ext_vector_type(8)));
typedef float  f32x4  __attribute__((ext_vector_type(4)));

__device__ __forceinline__ unsigned short f2bf(float x) {
    unsigned int u = __float_as_uint(x);
    unsigned int r = (u + 0x7fff + ((u >> 16) & 1)) >> 16;   // RNE
    return (unsigned short)r;
}
__device__ __forceinline__ float bflo(unsigned int u) { return __uint_as_float(u << 16); }
__device__ __forceinline__ float bfhi(unsigned int u) { return __uint_as_float(u & 0xffff0000u); }

// ---------------------------------------------------------------- pass 1 (fused)
// blocks [0,2500):       histogram + slot + fused r1 build
// blocks [2500,12500):   x[B,N,F0] fp32 -> z0[N,256] bf16
// blocks [12500,12660):  Bsw bf16 swizzled W1 prep
__global__ void histprep_kernel(const int* __restrict__ ei, const float* __restrict__ ev,
                                int* __restrict__ cnt, int* __restrict__ slot,
                                float* __restrict__ r1,
                                const float* __restrict__ x, unsigned short* __restrict__ z0,
                                const float* __restrict__ W1, unsigned short* __restrict__ Bsw) {
    int blk = blockIdx.x;
    if (blk < 2500) {
        int j = blk * 256 + threadIdx.x;
        int e = j / N_EDGES, t = j - e * N_EDGES;
        int r = ei[e * 2 * N_EDGES + t];
        slot[j] = atomicAdd(&cnt[e * N_NODES + r], 1);
        if (r == 0) {
            int c = ei[e * 2 * N_EDGES + N_EDGES + t];
            atomicAdd(&r1[e * N_NODES + c], ev[e * N_EDGES + t]);
        }
    } else if (blk < 12500) {
        int idx = (blk - 2500) * 256 + threadIdx.x;   // covers N*B*F0 exactly
        int n = idx >> 8, rem = idx & 255, b = rem >> 6, f = rem & 63;
        z0[idx] = f2bf(x[b * (N_NODES * F0) + n * F0 + f]);
    } else {
        int idx = (blk - 12500) * 256 + threadIdx.x;   // 160*256 = 40960 exactly
        int j    = idx & 7;
        int lane = (idx >> 3) & 63;
        int nt   = (idx >> 9) & 7;
        int kk   = (idx >> 12) & 1;
        int s    = idx >> 13;
        int k = kk * 32 + ((lane >> 4) << 3) + j;
        int n = nt * 16 + (lane & 15);
        int wi = k * 128 + n;
        float v;
        if (s == 0)      v = W1[0 * 8192 + wi] + W1[3 * 8192 + wi];
        else if (s == 1) v = W1[1 * 8192 + wi];
        else if (s == 2) v = W1[2 * 8192 + wi];
        else if (s == 3) v = W1[4 * 8192 + wi];
        else             v = W1[5 * 8192 + wi];
        Bsw[idx] = f2bf(v);
    }
}

// ---------------------------------------------------------------- pass 2: prefix scan
__global__ __launch_bounds__(1024) void prefix_kernel(const int* __restrict__ cnt,
                                                      int* __restrict__ rs) {
    __shared__ int wtot[16];
    int e = blockIdx.x, t = threadIdx.x;
    int lane = t & 63, w = t >> 6;
    int i0 = t * 10;
    int c[10];
    int local = 0;
    #pragma unroll
    for (int j = 0; j < 10; ++j) {
        int i = i0 + j;
        int v = (i < N_NODES) ? cnt[e * N_NODES + i] : 0;
        c[j] = local;
        local += v;
    }
    int inc = local;
    #pragma unroll
    for (int off = 1; off < 64; off <<= 1) {
        int u = __shfl_up(inc, off);
        if (lane >= off) inc += u;
    }
    if (lane == 63) wtot[w] = inc;
    __syncthreads();
    int base = 0;
    for (int k = 0; k < w; ++k) base += wtot[k];
    int excl = base + inc - local;
    #pragma unroll
    for (int j = 0; j < 10; ++j) {
        int i = i0 + j;
        if (i < N_NODES) rs[e * (N_NODES + 1) + i] = excl + c[j];
    }
    if (t == 1023) {
        int grand = 0;
        #pragma unroll
        for (int k = 0; k < 16; ++k) grand += wtot[k];
        rs[e * (N_NODES + 1) + N_NODES] = grand;
    }
}

// ---------------------------------------------------------------- pass 3: scatter + r2
__global__ void scatter_kernel(const int* __restrict__ ei, const float* __restrict__ ev,
                               const int* __restrict__ rs, const int* __restrict__ slot,
                               const float* __restrict__ r1,
                               int2* __restrict__ cev, float* __restrict__ r2) {
    int j = blockIdx.x * 256 + threadIdx.x;
    if (j >= NG * N_EDGES) return;
    int e = j / N_EDGES, t = j - e * N_EDGES;
    int r = ei[e * 2 * N_EDGES + t];
    int c = ei[e * 2 * N_EDGES + N_EDGES + t];
    float v = ev[e * N_EDGES + t];
    int pos = rs[e * (N_NODES + 1) + r] + slot[j];
    cev[e * N_EDGES + pos] = make_int2(c, __float_as_int(v));
    float w = r1[e * N_NODES + r];
    if (w != 0.f) atomicAdd(&r2[e * N_NODES + c], w * v);
}

// ---------------------------------------------------------------- SpMM tap-1 (full) + mark
// blocks [0,5000): wave = one (gso,row); lane-half x 8 bf16 = full node vector.
// blocks [5000,5040): build active list: n==0 or any r-weight nonzero.
__global__ __launch_bounds__(256) void spmm_full_kernel(
        const int2* __restrict__ cev, const int* __restrict__ rs,
        const unsigned short* __restrict__ zin0, const unsigned short* __restrict__ zin1,
        unsigned short* __restrict__ zout0, unsigned short* __restrict__ zout1,
        const float* __restrict__ r1, const float* __restrict__ r2,
        int* __restrict__ list, int* __restrict__ nact, int* __restrict__ pos0) {
    if (blockIdx.x >= 5000) {
        int n = (blockIdx.x - 5000) * 256 + threadIdx.x;
        if (n < N_NODES) {
            bool act = (n == 0) || r1[n] != 0.f || r2[n] != 0.f ||
                       r1[N_NODES + n] != 0.f || r2[N_NODES + n] != 0.f;
            if (act) {
                int p = atomicAdd(nact, 1);
                list[p] = n;
                if (n == 0) *pos0 = p;
            }
        }
        return;
    }
    int t = threadIdx.x;
    int w = t >> 6, l = t & 63;
    int rid = blockIdx.x * 4 + w;            // 0 .. 2*N_NODES-1
    int e = (rid >= N_NODES) ? 1 : 0;
    int i = rid - e * N_NODES;
    const unsigned short* zin = e ? zin1 : zin0;
    unsigned short* zout = e ? zout1 : zout0;
    const int2* cv = cev + e * N_EDGES;
    int s    = rs[e * (N_NODES + 1) + i];
    int send = rs[e * (N_NODES + 1) + i + 1];
    int hf = l >> 5, li = l & 31;
    float acc[8];
    #pragma unroll
    for (int j = 0; j < 8; ++j) acc[j] = 0.f;

    int p = s + hf;
    for (; p + 2 < send; p += 4) {
        int2 e0 = cv[p];
        int2 e1 = cv[p + 2];
        int c0 = e0.x; float v0 = __int_as_float(e0.y);
        int c1 = e1.x; float v1 = __int_as_float(e1.y);
        uint4 za = *(const uint4*)&zin[c0 * 256 + li * 8];
        uint4 zb = *(const uint4*)&zin[c1 * 256 + li * 8];
        acc[0] += v0 * bflo(za.x) + v1 * bflo(zb.x);
        acc[1] += v0 * bfhi(za.x) + v1 * bfhi(zb.x);
        acc[2] += v0 * bflo(za.y) + v1 * bflo(zb.y);
        acc[3] += v0 * bfhi(za.y) + v1 * bfhi(zb.y);
        acc[4] += v0 * bflo(za.z) + v1 * bflo(zb.z);
        acc[5] += v0 * bfhi(za.z) + v1 * bfhi(zb.z);
        acc[6] += v0 * bflo(za.w) + v1 * bflo(zb.w);
        acc[7] += v0 * bfhi(za.w) + v1 * bfhi(zb.w);
    }
    for (; p < send; p += 2) {
        int2 e0 = cv[p];
        int c0 = e0.x; float v0 = __int_as_float(e0.y);
        uint4 za = *(const uint4*)&zin[c0 * 256 + li * 8];
        acc[0] += v0 * bflo(za.x); acc[1] += v0 * bfhi(za.x);
        acc[2] += v0 * bflo(za.y); acc[3] += v0 * bfhi(za.y);
        acc[4] += v0 * bflo(za.z); acc[5] += v0 * bfhi(za.z);
        acc[6] += v0 * bflo(za.w); acc[7] += v0 * bfhi(za.w);
    }
    #pragma unroll
    for (int j = 0; j < 8; ++j) acc[j] += __shfl_xor(acc[j], 32);
    if (hf == 0) {
        uint4 o;
        unsigned int r[8];
        #pragma unroll
        for (int j = 0; j < 8; ++j) r[j] = f2bf(acc[j]);
        o.x = r[0] | (r[1] << 16);
        o.y = r[2] | (r[3] << 16);
        o.z = r[4] | (r[5] << 16);
        o.w = r[6] | (r[7] << 16);
        *(uint4*)&zout[i * 256 + li * 8] = o;
    }
}

// ---------------------------------------------------------------- SpMM tap-2 (active rows only)
__global__ __launch_bounds__(256) void spmm_act_kernel(
        const int2* __restrict__ cev, const int* __restrict__ rs,
        const unsigned short* __restrict__ zin0, const unsigned short* __restrict__ zin1,
        unsigned short* __restrict__ zout0, unsigned short* __restrict__ zout1,
        const int* __restrict__ list, const int* __restrict__ nact) {
    int t = threadIdx.x;
    int w = t >> 6, l = t & 63;
    int rid = blockIdx.x * 4 + w;
    int na = *nact;
    if (rid >= 2 * na) return;
    int e = (rid >= na) ? 1 : 0;
    int i = list[rid - e * na];
    const unsigned short* zin = e ? zin1 : zin0;
    unsigned short* zout = e ? zout1 : zout0;
    const int2* cv = cev + e * N_EDGES;
    int s    = rs[e * (N_NODES + 1) + i];
    int send = rs[e * (N_NODES + 1) + i + 1];
    int hf = l >> 5, li = l & 31;
    float acc[8];
    #pragma unroll
    for (int j = 0; j < 8; ++j) acc[j] = 0.f;

    int p = s + hf;
    for (; p + 2 < send; p += 4) {
        int2 e0 = cv[p];
        int2 e1 = cv[p + 2];
        int c0 = e0.x; float v0 = __int_as_float(e0.y);
        int c1 = e1.x; float v1 = __int_as_float(e1.y);
        uint4 za = *(const uint4*)&zin[c0 * 256 + li * 8];
        uint4 zb = *(const uint4*)&zin[c1 * 256 + li * 8];
        acc[0] += v0 * bflo(za.x) + v1 * bflo(zb.x);
        acc[1] += v0 * bfhi(za.x) + v1 * bfhi(zb.x);
        acc[2] += v0 * bflo(za.y) + v1 * bflo(zb.y);
        acc[3] += v0 * bfhi(za.y) + v1 * bfhi(zb.y);
        acc[4] += v0 * bflo(za.z) + v1 * bflo(zb.z);
        acc[5] += v0 * bfhi(za.z) + v1 * bfhi(zb.z);
        acc[6] += v0 * bflo(za.w) + v1 * bflo(zb.w);
        acc[7] += v0 * bfhi(za.w) + v1 * bfhi(zb.w);
    }
    for (; p < send; p += 2) {
        int2 e0 = cv[p];
        int c0 = e0.x; float v0 = __int_as_float(e0.y);
        uint4 za = *(const uint4*)&zin[c0 * 256 + li * 8];
        acc[0] += v0 * bflo(za.x); acc[1] += v0 * bfhi(za.x);
        acc[2] += v0 * bflo(za.y); acc[3] += v0 * bfhi(za.y);
        acc[4] += v0 * bflo(za.z); acc[5] += v0 * bfhi(za.z);
        acc[6] += v0 * bflo(za.w); acc[7] += v0 * bfhi(za.w);
    }
    #pragma unroll
    for (int j = 0; j < 8; ++j) acc[j] += __shfl_xor(acc[j], 32);
    if (hf == 0) {
        uint4 o;
        unsigned int r[8];
        #pragma unroll
        for (int j = 0; j < 8; ++j) r[j] = f2bf(acc[j]);
        o.x = r[0] | (r[1] << 16);
        o.y = r[2] | (r[3] << 16);
        o.z = r[4] | (r[5] << 16);
        o.w = r[6] | (r[7] << 16);
        *(uint4*)&zout[i * 256 + li * 8] = o;
    }
}

// ---------------------------------------------------------------- layer-1 MFMA GEMM (active rows)
// hA[m,0:128] = b1 + sum_s z_s[node(m), b(m), 0:64] @ Wc[s];  m = a*4+b, a<nact
__global__ __launch_bounds__(256) void gemm_kernel(
        const unsigned short* __restrict__ z0,  const unsigned short* __restrict__ z11,
        const unsigned short* __restrict__ z12, const unsigned short* __restrict__ z21,
        const unsigned short* __restrict__ z22, const unsigned short* __restrict__ Bsw,
        const float* __restrict__ b1, float* __restrict__ hA,
        const int* __restrict__ list, const int* __restrict__ nact) {
    int t = threadIdx.x;
    int w = t >> 6, l = t & 63;
    int M = 4 * (*nact);
    int m0 = blockIdx.x * 64 + w * 16;
    if (m0 >= M) return;
    int am  = l & 15;           // A row within tile
    int ak8 = (l >> 4) << 3;    // A k-offset within 32-wide K step
    int m = m0 + am;
    if (m >= M) m = M - 1;      // clamp (stores are guarded)
    int zoff = list[m >> 2] * 256 + (m & 3) * 64;
    const unsigned short* Z[5] = { z0, z11, z12, z21, z22 };
    f32x4 acc[8];
    #pragma unroll
    for (int nt = 0; nt < 8; ++nt) acc[nt] = (f32x4){0.f, 0.f, 0.f, 0.f};

    #pragma unroll
    for (int s = 0; s < 5; ++s) {
        const unsigned short* A = Z[s] + zoff;
        #pragma unroll
        for (int kk = 0; kk < 2; ++kk) {
            bf16x8 a = *(const bf16x8*)(A + kk * 32 + ak8);
            const unsigned short* B = Bsw + (((s * 2 + kk) * 8) * 64 + l) * 8;
            #pragma unroll
            for (int nt = 0; nt < 8; ++nt) {
                bf16x8 b = *(const bf16x8*)(B + nt * 512);
                acc[nt] = __builtin_amdgcn_mfma_f32_16x16x32_bf16(a, b, acc[nt], 0, 0, 0);
            }
        }
    }
    // C/D: lane holds D[m = (l>>4)*4 + reg][n = l&15]
    int mrow = m0 + ((l >> 4) << 2);
    int ncol = l & 15;
    #pragma unroll
    for (int nt = 0; nt < 8; ++nt) {
        int n = nt * 16 + ncol;
        float bias = b1[n];
        #pragma unroll
        for (int r = 0; r < 4; ++r) {
            if (mrow + r < M) hA[(mrow + r) * 128 + n] = acc[nt][r] + bias;
        }
    }
}

// q[ek][b*128+f1] = sum_a r_ek[list[a]] * hA[a*512 + b*128 + f1]
__global__ void q_kernel(const float* __restrict__ hA, const float* __restrict__ r1,
                         const float* __restrict__ r2, float* __restrict__ q,
                         const int* __restrict__ list, const int* __restrict__ nact) {
    int t = threadIdx.x;                 // 512 threads = (b,f1)
    int na = *nact;
    int a0 = blockIdx.x * 64;
    if (a0 >= na) return;
    int a1 = a0 + 64; if (a1 > na) a1 = na;
    float s0 = 0.f, s1 = 0.f, s2 = 0.f, s3 = 0.f;
    for (int a = a0; a < a1; ++a) {
        int n = list[a];
        float w0 = r1[n];
        float w1 = r2[n];
        float w2 = r1[N_NODES + n];
        float w3 = r2[N_NODES + n];
        if (w0 == 0.f && w1 == 0.f && w2 == 0.f && w3 == 0.f) continue;
        float hv = hA[a * 512 + t];
        s0 += w0 * hv; s1 += w1 * hv; s2 += w2 * hv; s3 += w3 * hv;
    }
    if (s0 != 0.f) atomicAdd(&q[0 * 512 + t], s0);
    if (s1 != 0.f) atomicAdd(&q[1 * 512 + t], s1);
    if (s2 != 0.f) atomicAdd(&q[2 * 512 + t], s2);
    if (s3 != 0.f) atomicAdd(&q[3 * 512 + t], s3);
}

// out[b,f2] = b2 + hA[pos0,b,:]·(W2[0,0]+W2[1,0]) + q0·W2[0,1] + q1·W2[0,2] + q2·W2[1,1] + q3·W2[1,2]
__global__ void final_kernel(const float* __restrict__ hA, const float* __restrict__ q,
                             const float* __restrict__ W2, const float* __restrict__ b2,
                             float* __restrict__ out, const int* __restrict__ pos0) {
    int t = threadIdx.x;               // 512
    int b = t >> 7, f2 = t & 127;
    int f1_0 = blockIdx.x * 16;        // 8 blocks x 16 f1 each
    const float* h0 = hA + (*pos0) * 512;
    float acc = (blockIdx.x == 0) ? b2[f2] : 0.f;
    for (int f1 = f1_0; f1 < f1_0 + 16; ++f1) {
        int wi = f1 * 128 + f2;
        float w00 = W2[0 * 16384 + wi] + W2[3 * 16384 + wi];
        acc += h0[b * 128 + f1] * w00;
        acc += q[0 * 512 + b * 128 + f1] * W2[1 * 16384 + wi];
        acc += q[1 * 512 + b * 128 + f1] * W2[2 * 16384 + wi];
        acc += q[2 * 512 + b * 128 + f1] * W2[4 * 16384 + wi];
        acc += q[3 * 512 + b * 128 + f1] * W2[5 * 16384 + wi];
    }
    atomicAdd(&out[b * 128 + f2], acc);
}

// ----------------------------------------------------------------
extern "C" void kernel_launch(void* const* d_in, const int* in_sizes, int n_in,
                              void* d_out, int out_size, void* d_ws, size_t ws_size,
                              hipStream_t stream) {
    const float* x  = (const float*)d_in[0];
    const int*   ei = (const int*)d_in[1];
    const float* ev = (const float*)d_in[2];
    const float* W1 = (const float*)d_in[3];
    const float* b1 = (const float*)d_in[4];
    const float* W2 = (const float*)d_in[5];
    const float* b2 = (const float*)d_in[6];
    float* out = (float*)d_out;

    char* ws = (char*)d_ws;
    size_t off = 0;
    auto alloc = [&](size_t bytes) { size_t o = off; off += (bytes + 255) & ~(size_t)255; return o; };
    const size_t ZB  = (size_t)N_NODES * BATCH * F0 * 2;      // 5.12 MB per bf16 z buffer
    size_t o_z0  = alloc(ZB);
    size_t o_z11 = alloc(ZB);
    size_t o_z12 = alloc(ZB);
    size_t o_z21 = alloc(ZB);
    size_t o_z22 = alloc(ZB);
    size_t o_h   = alloc((size_t)N_NODES * BATCH * F1 * 4);   // hA (compact, worst case full)
    size_t o_cev  = alloc((size_t)NG * N_EDGES * 8);          // interleaved (col, val)
    size_t o_slot = alloc((size_t)NG * N_EDGES * 4);
    size_t o_rs   = alloc((size_t)NG * (N_NODES + 1) * 4);
    size_t o_bsw  = alloc((size_t)5 * 2 * 8 * 64 * 8 * 2);    // 80 KB bf16 swizzled W
    size_t o_list = alloc((size_t)N_NODES * 4);
    size_t o_zero = off;                                      // zeroed region starts here
    size_t o_cnt    = alloc((size_t)NG * N_NODES * 4);
    size_t o_r      = alloc((size_t)2 * NG * N_NODES * 4);    // r1[2][N] then r2[2][N]
    size_t o_q      = alloc((size_t)4 * 512 * 4);
    size_t o_misc   = alloc(2 * 4);                           // nact, pos0
    size_t zero_bytes = off - o_zero;

    unsigned short* z0  = (unsigned short*)(ws + o_z0);
    unsigned short* z11 = (unsigned short*)(ws + o_z11);
    unsigned short* z12 = (unsigned short*)(ws + o_z12);
    unsigned short* z21 = (unsigned short*)(ws + o_z21);
    unsigned short* z22 = (unsigned short*)(ws + o_z22);
    float* hA  = (float*)(ws + o_h);
    int2*  cev  = (int2*)(ws + o_cev);
    int*   slot = (int*)(ws + o_slot);
    int*   rs   = (int*)(ws + o_rs);
    unsigned short* Bsw = (unsigned short*)(ws + o_bsw);
    int*   list = (int*)(ws + o_list);
    int*   cnt  = (int*)(ws + o_cnt);
    float* r1   = (float*)(ws + o_r);
    float* r2   = r1 + 2 * N_NODES;
    float* q    = (float*)(ws + o_q);
    int*   nact = (int*)(ws + o_misc);
    int*   pos0 = nact + 1;

    hipMemsetAsync(ws + o_zero, 0, zero_bytes, stream);
    hipMemsetAsync(out, 0, 512 * sizeof(float), stream);

    histprep_kernel<<<12660, 256, 0, stream>>>(ei, ev, cnt, slot, r1, x, z0, W1, Bsw);
    prefix_kernel  <<<2,    1024, 0, stream>>>(cnt, rs);
    scatter_kernel <<<2500,  256, 0, stream>>>(ei, ev, rs, slot, r1, cev, r2);
    spmm_full_kernel<<<5040, 256, 0, stream>>>(cev, rs, z0, z0, z11, z21,
                                               r1, r2, list, nact, pos0);
    spmm_act_kernel<<<5000,  256, 0, stream>>>(cev, rs, z11, z21, z12, z22, list, nact);
    gemm_kernel    <<<625,   256, 0, stream>>>(z0, z11, z12, z21, z22, Bsw, b1, hA, list, nact);
    q_kernel       <<<157,   512, 0, stream>>>(hA, r1, r2, q, list, nact);
    final_kernel   <<<8,     512, 0, stream>>>(hA, q, W2, b2, out, pos0);
}